// Round 7
// baseline (346.873 us; speedup 1.0000x reference)
//
#include <hip/hip_runtime.h>
#include <hip/hip_bf16.h>
#include <cstdint>

#define BB 2
#define TT 2048
#define DD 1024
#define HH 16
#define DH 64
#define MM (BB*TT)      // 4096 rows
constexpr int KDIM = 1024;
constexpr int NDIM = 1024;

typedef __bf16 bf16;
typedef __attribute__((ext_vector_type(8))) __bf16 bf16x8;
typedef __attribute__((ext_vector_type(4))) float f32x4;

#define MFMA(a,b,c) __builtin_amdgcn_mfma_f32_16x16x32_bf16((a),(b),(c),0,0,0)

// ---------------- elementwise: f32 -> bf16 cast (x -> xb) ----------------
__global__ __launch_bounds__(256) void k_cvt(const float* __restrict__ in, bf16* __restrict__ outp) {
    size_t i = ((size_t)blockIdx.x * 256 + threadIdx.x) * 8;
    float4 a = *(const float4*)(in + i);
    float4 b = *(const float4*)(in + i + 4);
    bf16x8 r;
    r[0] = (bf16)a.x; r[1] = (bf16)a.y; r[2] = (bf16)a.z; r[3] = (bf16)a.w;
    r[4] = (bf16)b.x; r[5] = (bf16)b.y; r[6] = (bf16)b.z; r[7] = (bf16)b.w;
    *(bf16x8*)(outp + i) = r;
}

// ---------------- transpose + cast: W (K x N) f32 -> W^T (N x K) bf16 ----------------
__global__ __launch_bounds__(256) void k_transpose_cvt(const float* __restrict__ in, bf16* __restrict__ outp) {
    __shared__ float tile[64][65];
    const int tx = threadIdx.x & 63;
    const int ty = threadIdx.x >> 6;
    const int r0 = blockIdx.y * 64, c0 = blockIdx.x * 64;
#pragma unroll
    for (int i = 0; i < 16; ++i) {
        int rr = ty * 16 + i;
        tile[rr][tx] = in[(size_t)(r0 + rr) * 1024 + c0 + tx];
    }
    __syncthreads();
#pragma unroll
    for (int i = 0; i < 16; ++i) {
        int rr = ty * 16 + i;
        outp[(size_t)(c0 + rr) * 1024 + r0 + tx] = (bf16)tile[tx][rr];
    }
}

// ---------------- GEMM: A (M x K, bf16 rm) @ Bt (N x K, bf16 rm) -> C f32 (bf16-rounded) ----
#define BM 128
#define BN 128
#define BKT 64

__device__ __forceinline__ void gemm_core(const bf16* __restrict__ A, const bf16* __restrict__ Bt,
                                          float* __restrict__ Cc) {
    __shared__ __align__(16) bf16 As[BM * BKT];
    __shared__ __align__(16) bf16 Bs[BN * BKT];
    const int tid  = threadIdx.x;
    const int lane = tid & 63;
    const int w    = tid >> 6;
    const int wr   = w >> 1, wc = w & 1;
    const int bm   = blockIdx.x * BM;
    const int bn   = blockIdx.y * BN;

    f32x4 acc[4][4];
#pragma unroll
    for (int m_ = 0; m_ < 4; ++m_)
#pragma unroll
        for (int n = 0; n < 4; ++n) acc[m_][n] = (f32x4){0.f, 0.f, 0.f, 0.f};

    const int srow = tid >> 3;
    const int sc   = tid & 7;
    const int sp   = sc ^ (srow & 7);
    const int fr   = lane & 15;
    const int fg   = lane >> 4;

    const bf16* Ap = A  + (size_t)(bm + srow) * KDIM + sc * 8;
    const bf16* Bp = Bt + (size_t)(bn + srow) * KDIM + sc * 8;

    for (int kt = 0; kt < KDIM; kt += BKT) {
        bf16x8 ar[4], br[4];
#pragma unroll
        for (int i = 0; i < 4; ++i) {
            ar[i] = *(const bf16x8*)(Ap + (size_t)i * 32 * KDIM + kt);
            br[i] = *(const bf16x8*)(Bp + (size_t)i * 32 * KDIM + kt);
        }
        __syncthreads();
#pragma unroll
        for (int i = 0; i < 4; ++i) {
            *(bf16x8*)(As + (i * 32 + srow) * BKT + sp * 8) = ar[i];
            *(bf16x8*)(Bs + (i * 32 + srow) * BKT + sp * 8) = br[i];
        }
        __syncthreads();
#pragma unroll
        for (int s = 0; s < 2; ++s) {
            bf16x8 af[4], bfv[4];
#pragma unroll
            for (int m_ = 0; m_ < 4; ++m_) {
                int row = wr * 64 + m_ * 16 + fr;
                int p   = (s * 4 + fg) ^ (row & 7);
                af[m_] = *(const bf16x8*)(As + row * BKT + p * 8);
            }
#pragma unroll
            for (int n = 0; n < 4; ++n) {
                int row = wc * 64 + n * 16 + fr;
                int p   = (s * 4 + fg) ^ (row & 7);
                bfv[n] = *(const bf16x8*)(Bs + row * BKT + p * 8);
            }
#pragma unroll
            for (int m_ = 0; m_ < 4; ++m_)
#pragma unroll
                for (int n = 0; n < 4; ++n)
                    acc[m_][n] = MFMA(af[m_], bfv[n], acc[m_][n]);
        }
    }
#pragma unroll
    for (int m_ = 0; m_ < 4; ++m_) {
        int row0 = bm + wr * 64 + m_ * 16 + fg * 4;
#pragma unroll
        for (int j = 0; j < 4; ++j)
#pragma unroll
            for (int n = 0; n < 4; ++n) {
                int col = bn + wc * 64 + n * 16 + fr;
                Cc[(size_t)(row0 + j) * NDIM + col] = (float)((bf16)acc[m_][n][j]);
            }
    }
}

__global__ __launch_bounds__(256) void k_gemm(const bf16* __restrict__ A, const bf16* __restrict__ Bt,
                                              float* __restrict__ Cc) {
    gemm_core(A, Bt, Cc);
}

__global__ __launch_bounds__(256) void k_gemm_qkv(const bf16* __restrict__ A, const bf16* __restrict__ WtBase,
                                                  float* __restrict__ outBase) {
    int z = blockIdx.z;
    gemm_core(A, WtBase + (size_t)z * (DD * DD), outBase + (size_t)z * ((size_t)MM * DD));
}

// ---------------- Wb (1024x16 f32) -> fragment-ordered bf16 [s][lane][e] ----------------
__global__ __launch_bounds__(256) void k_wbfrag(const float* __restrict__ Wb, bf16* __restrict__ wf) {
    int i = blockIdx.x * 256 + threadIdx.x;   // 2048 slots (32 s-steps x 64 lanes)
    int s = i >> 6, l = i & 63;
    int h = l & 15, kb = (l >> 4) * 8;
    bf16x8 r;
#pragma unroll
    for (int e = 0; e < 8; ++e) r[e] = (bf16)Wb[(size_t)(s * 32 + kb + e) * HH + h];
    *(bf16x8*)(wf + (size_t)i * 8) = r;
}

// ---------------- beta = 2*sigmoid(bf16round(xb @ Wb_bf16)) via MFMA ----------------
__global__ __launch_bounds__(64) void k_beta2(const bf16* __restrict__ xb, const bf16* __restrict__ wf,
                                              float* __restrict__ beta) {
    const int lane = threadIdx.x;
    const int fr = lane & 15, fg = lane >> 4;
    const int tile = blockIdx.x;
    const bf16* ap = xb + (size_t)(tile * 16 + fr) * DD + fg * 8;
    f32x4 acc = (f32x4){0.f, 0.f, 0.f, 0.f};
#pragma unroll
    for (int s = 0; s < 32; ++s) {
        bf16x8 a = *(const bf16x8*)(ap + s * 32);
        bf16x8 b = *(const bf16x8*)(wf + ((size_t)s * 64 + lane) * 8);
        acc = MFMA(a, b, acc);
    }
#pragma unroll
    for (int j = 0; j < 4; ++j) {
        float rr = (float)((bf16)acc[j]);       // jnp bf16 matmul rounds before astype(f32)
        beta[(size_t)(tile * 16 + fg * 4 + j) * HH + fr] = 2.f / (1.f + expf(-rr));
    }
}

// ---------------- silu + per-head l2norm, in place (q and k) ----------------
__global__ __launch_bounds__(256) void k_actnorm(float* __restrict__ a) {
    size_t row = (size_t)blockIdx.x * 4 + (threadIdx.x >> 6);
    int lane = threadIdx.x & 63;
    float x = a[row * 64 + lane];
    float e = x / (1.f + expf(-x));
    float ss = e * e;
#pragma unroll
    for (int m = 1; m < 64; m <<= 1) ss += __shfl_xor(ss, m);
    a[row * 64 + lane] = e * rsqrtf(ss + 1e-6f);
}

// ---------------- OLD sequential delta-rule scan (fallback if ws too small) ----------------
__global__ __launch_bounds__(256) void k_scan(const float* __restrict__ Qv, const float* __restrict__ Kv,
                                              const float* __restrict__ Vv, const float* __restrict__ Bv,
                                              float* __restrict__ Ov) {
    const int bh = blockIdx.x;
    const int b = bh >> 4, h = bh & 15;
    const int tid = threadIdx.x;
    const int r   = tid >> 2;
    const int seg = tid & 3;
    float S[16];
#pragma unroll
    for (int j = 0; j < 16; ++j) S[j] = 0.f;
    const size_t base = ((size_t)b * TT) * DD + (size_t)h * DH;
    const float* kp = Kv + base + seg * 16;
    const float* qp = Qv + base + seg * 16;
    const float* vp = Vv + base + r;
    const float* bp = Bv + ((size_t)b * TT) * HH + h;
    float* op = Ov + base + r;

    float4 k0, k1, k2, k3, q0, q1, q2, q3;
    float vv, bt;
    k0 = *(const float4*)(kp + 0);  k1 = *(const float4*)(kp + 4);
    k2 = *(const float4*)(kp + 8);  k3 = *(const float4*)(kp + 12);
    q0 = *(const float4*)(qp + 0);  q1 = *(const float4*)(qp + 4);
    q2 = *(const float4*)(qp + 8);  q3 = *(const float4*)(qp + 12);
    vv = *vp; bt = *bp;

    for (int t = 0; t < TT; ++t) {
        float4 nk0, nk1, nk2, nk3, nq0, nq1, nq2, nq3;
        float nvv = 0.f, nbt = 0.f;
        if (t + 1 < TT) {
            const float* kn = kp + (size_t)(t + 1) * DD;
            const float* qn = qp + (size_t)(t + 1) * DD;
            nk0 = *(const float4*)(kn + 0);  nk1 = *(const float4*)(kn + 4);
            nk2 = *(const float4*)(kn + 8);  nk3 = *(const float4*)(kn + 12);
            nq0 = *(const float4*)(qn + 0);  nq1 = *(const float4*)(qn + 4);
            nq2 = *(const float4*)(qn + 8);  nq3 = *(const float4*)(qn + 12);
            nvv = vp[(size_t)(t + 1) * DD];
            nbt = bp[(size_t)(t + 1) * HH];
        }
        float a0, a1, a2, a3;
        a0 = S[0] * k0.x;  a1 = S[1] * k0.y;  a2 = S[2] * k0.z;  a3 = S[3] * k0.w;
        a0 = fmaf(S[4],  k1.x, a0); a1 = fmaf(S[5],  k1.y, a1); a2 = fmaf(S[6],  k1.z, a2); a3 = fmaf(S[7],  k1.w, a3);
        a0 = fmaf(S[8],  k2.x, a0); a1 = fmaf(S[9],  k2.y, a1); a2 = fmaf(S[10], k2.z, a2); a3 = fmaf(S[11], k2.w, a3);
        a0 = fmaf(S[12], k3.x, a0); a1 = fmaf(S[13], k3.y, a1); a2 = fmaf(S[14], k3.z, a2); a3 = fmaf(S[15], k3.w, a3);
        float sk = (a0 + a1) + (a2 + a3);
        sk += __shfl_xor(sk, 1); sk += __shfl_xor(sk, 2);
        const float wgt = bt * (vv - sk);
        float o0, o1, o2, o3;
        S[0]  = fmaf(wgt, k0.x, S[0]);  o0 = S[0] * q0.x;
        S[1]  = fmaf(wgt, k0.y, S[1]);  o1 = S[1] * q0.y;
        S[2]  = fmaf(wgt, k0.z, S[2]);  o2 = S[2] * q0.z;
        S[3]  = fmaf(wgt, k0.w, S[3]);  o3 = S[3] * q0.w;
        S[4]  = fmaf(wgt, k1.x, S[4]);  o0 = fmaf(S[4],  q1.x, o0);
        S[5]  = fmaf(wgt, k1.y, S[5]);  o1 = fmaf(S[5],  q1.y, o1);
        S[6]  = fmaf(wgt, k1.z, S[6]);  o2 = fmaf(S[6],  q1.z, o2);
        S[7]  = fmaf(wgt, k1.w, S[7]);  o3 = fmaf(S[7],  q1.w, o3);
        S[8]  = fmaf(wgt, k2.x, S[8]);  o0 = fmaf(S[8],  q2.x, o0);
        S[9]  = fmaf(wgt, k2.y, S[9]);  o1 = fmaf(S[9],  q2.y, o1);
        S[10] = fmaf(wgt, k2.z, S[10]); o2 = fmaf(S[10], q2.z, o2);
        S[11] = fmaf(wgt, k2.w, S[11]); o3 = fmaf(S[11], q2.w, o3);
        S[12] = fmaf(wgt, k3.x, S[12]); o0 = fmaf(S[12], q3.x, o0);
        S[13] = fmaf(wgt, k3.y, S[13]); o1 = fmaf(S[13], q3.y, o1);
        S[14] = fmaf(wgt, k3.z, S[14]); o2 = fmaf(S[14], q3.z, o2);
        S[15] = fmaf(wgt, k3.w, S[15]); o3 = fmaf(S[15], q3.w, o3);
        float oo = (o0 + o1) + (o2 + o3);
        oo += __shfl_xor(oo, 1); oo += __shfl_xor(oo, 2);
        if (seg == 0) op[(size_t)t * DD] = oo;
        k0 = nk0; k1 = nk1; k2 = nk2; k3 = nk3;
        q0 = nq0; q1 = nq1; q2 = nq2; q3 = nq3;
        vv = nvv; bt = nbt;
    }
}

// =================== CHUNKED WY SCAN ===================
// Chunk C=64. k_prep (parallel): A = tril(beta*K.K^T), solve (I+A)[Uv|Uk] = diag(beta)[V|K],
// L = tril(Q.K^T). k_scan2 (sequential, wave-specialized):
//   S-waves (0-3): U_c = Uv_c - Uk_c*S_c ; S_{c+1} = S_c + K_c^T U_c   (critical path)
//   O-waves (4-7): O_c = Q_c*S_c + L_c*U_c, one chunk behind, dbuf ShT/Ut (off critical path)

__device__ __forceinline__ int uv_idx(int t, int vv) {
    // fragment-order so phase2 wave w loads f32x4 at ((w*4+vt)*64 + lane)*4
    return (((t >> 4) * 4 + (vv >> 4)) * 64 + (((t >> 2) & 3) * 16 + (vv & 15))) * 4 + (t & 3);
}

__global__ __launch_bounds__(256, 3) void k_prep(
        const float* __restrict__ q, const float* __restrict__ k, const float* __restrict__ v,
        const float* __restrict__ beta,
        bf16* __restrict__ L_out, bf16* __restrict__ nUk_h, bf16* __restrict__ nUk_l,
        bf16* __restrict__ Kt_h, bf16* __restrict__ Kt_l, float* __restrict__ Uv_out) {
    __shared__ float Ash[64][65];
    __shared__ bf16 Khi[64][72], Klo[64][72];
    __shared__ float bsh[64];

    const int tid = threadIdx.x;
    const int c = blockIdx.x, bh = blockIdx.y, b = bh >> 4, h = bh & 15;
    const int row0 = b * TT + c * 64, col0 = h * 64;
    const size_t off = ((size_t)bh * 32 + c) * 4096;
    const int lane = tid & 63, w = tid >> 6;
    const int fr = lane & 15, fg = lane >> 4;

    // ---- early global loads ----
    const int cslice = (w & 1) * 32;
    const float* rp = ((w >= 2) ? k : v) + (size_t)(row0 + lane) * DD + col0 + cslice;
    float4 rv[8];
#pragma unroll
    for (int a = 0; a < 8; ++a) rv[a] = *(const float4*)(rp + a * 4);
    const float* qfp = q + (size_t)(row0 + w * 16 + fr) * DD + col0 + fg * 8;
    float4 qa = *(const float4*)qfp, qb = *(const float4*)(qfp + 4);
    float4 qc = *(const float4*)(qfp + 32), qd = *(const float4*)(qfp + 36);
    const int tr = tid >> 2, cs = (tid & 3) * 16;
    float4 kv[4];
    const size_t rb = (size_t)(row0 + tr) * DD + col0 + cs;
#pragma unroll
    for (int j = 0; j < 4; ++j) kv[j] = *(const float4*)(k + rb + j * 4);

    if (tid < 64) bsh[tid] = beta[(size_t)(row0 + tid) * HH + h];
#pragma unroll
    for (int j = 0; j < 4; ++j) {
        int cb = cs + j * 4;
        float a0 = kv[j].x, a1 = kv[j].y, a2 = kv[j].z, a3 = kv[j].w;
        bf16 h0 = (bf16)a0, h1 = (bf16)a1, h2 = (bf16)a2, h3 = (bf16)a3;
        Khi[tr][cb] = h0; Khi[tr][cb+1] = h1; Khi[tr][cb+2] = h2; Khi[tr][cb+3] = h3;
        Klo[tr][cb]   = (bf16)(a0 - (float)h0);
        Klo[tr][cb+1] = (bf16)(a1 - (float)h1);
        Klo[tr][cb+2] = (bf16)(a2 - (float)h2);
        Klo[tr][cb+3] = (bf16)(a3 - (float)h3);
    }
    __syncthreads();

    // ---- MFMA: A_raw = K.K^T (bf16x2), L = tril(Q.K^T) ----
    {
        bf16x8 aqh0, aqh1;
        aqh0[0]=(bf16)qa.x; aqh0[1]=(bf16)qa.y; aqh0[2]=(bf16)qa.z; aqh0[3]=(bf16)qa.w;
        aqh0[4]=(bf16)qb.x; aqh0[5]=(bf16)qb.y; aqh0[6]=(bf16)qb.z; aqh0[7]=(bf16)qb.w;
        aqh1[0]=(bf16)qc.x; aqh1[1]=(bf16)qc.y; aqh1[2]=(bf16)qc.z; aqh1[3]=(bf16)qc.w;
        aqh1[4]=(bf16)qd.x; aqh1[5]=(bf16)qd.y; aqh1[6]=(bf16)qd.z; aqh1[7]=(bf16)qd.w;
        f32x4 accA[4], accL[4];
#pragma unroll
        for (int it = 0; it < 4; ++it) { accA[it] = (f32x4){0,0,0,0}; accL[it] = (f32x4){0,0,0,0}; }
        bf16x8 akh0 = *(const bf16x8*)&Khi[w*16+fr][fg*8];
        bf16x8 akh1 = *(const bf16x8*)&Khi[w*16+fr][fg*8+32];
        bf16x8 akl0 = *(const bf16x8*)&Klo[w*16+fr][fg*8];
        bf16x8 akl1 = *(const bf16x8*)&Klo[w*16+fr][fg*8+32];
#pragma unroll
        for (int it = 0; it < 4; ++it) {
            bf16x8 bh0 = *(const bf16x8*)&Khi[it*16+fr][fg*8];
            bf16x8 bl0 = *(const bf16x8*)&Klo[it*16+fr][fg*8];
            accA[it] = MFMA(akh0, bh0, accA[it]);
            accA[it] = MFMA(akh0, bl0, accA[it]);
            accA[it] = MFMA(akl0, bh0, accA[it]);
            accL[it] = MFMA(aqh0, bh0, accL[it]);
            bf16x8 bh1 = *(const bf16x8*)&Khi[it*16+fr][fg*8+32];
            bf16x8 bl1 = *(const bf16x8*)&Klo[it*16+fr][fg*8+32];
            accA[it] = MFMA(akh1, bh1, accA[it]);
            accA[it] = MFMA(akh1, bl1, accA[it]);
            accA[it] = MFMA(akl1, bh1, accA[it]);
            accL[it] = MFMA(aqh1, bh1, accL[it]);
        }
#pragma unroll
        for (int it = 0; it < 4; ++it)
#pragma unroll
            for (int j = 0; j < 4; ++j) {
                int tg = w * 16 + fg * 4 + j, ig = it * 16 + fr;
                Ash[tg][ig] = (ig < tg) ? bsh[tg] * accA[it][j] : 0.f;
                L_out[off + tg * 64 + ig] = (ig <= tg) ? (bf16)accL[it][j] : (bf16)0.f;
            }
    }
    __syncthreads();

    // ---- barrier-free substitution: X[t][col] in registers, lane=row ----
    float bt = bsh[lane];
    float X[32];
#pragma unroll
    for (int a = 0; a < 8; ++a) {
        X[a*4+0] = bt * rv[a].x; X[a*4+1] = bt * rv[a].y;
        X[a*4+2] = bt * rv[a].z; X[a*4+3] = bt * rv[a].w;
    }
#pragma unroll 1
    for (int i = 0; i < 63; ++i) {
        float a = Ash[lane][i];          // conflict-free: stride-65, 2 lanes/bank
#pragma unroll
        for (int j = 0; j < 32; ++j) {
            float s = __uint_as_float(__builtin_amdgcn_readlane(__float_as_uint(X[j]), i));
            X[j] = fmaf(-a, s, X[j]);    // a==0 for i>=lane (zero-padded A)
        }
    }

    // ---- outputs ----
    if (w < 2) {                         // V columns -> Uv (fp32, fragment order)
#pragma unroll
        for (int j = 0; j < 32; ++j)
            Uv_out[off + uv_idx(lane, cslice + j)] = X[j];
    } else {                             // K columns -> -Uk hi/lo
#pragma unroll
        for (int g = 0; g < 4; ++g) {
            bf16x8 hi8, lo8;
#pragma unroll
            for (int e = 0; e < 8; ++e) {
                float nk = -X[g*8+e];
                bf16 nh = (bf16)nk;
                hi8[e] = nh;
                lo8[e] = (bf16)(nk - (float)nh);
            }
            *(bf16x8*)(nUk_h + off + (size_t)lane*64 + cslice + g*8) = hi8;
            *(bf16x8*)(nUk_l + off + (size_t)lane*64 + cslice + g*8) = lo8;
        }
    }
#pragma unroll
    for (int j = 0; j < 16; ++j) {
        int vc = cs + j;
        Kt_h[off + (size_t)tr*64 + vc] = Khi[vc][tr];
        Kt_l[off + (size_t)tr*64 + vc] = Klo[vc][tr];
    }
}

// ---- wave-specialized scan2: 8 waves (0-3 = S critical path, 4-7 = O path, 1 chunk behind)
// o written FRAGMENT-ORDERED: of[off(c) + ((w*4+vt)*64 + lane)*4 + j]  (coalesced f32x4)
__global__ __launch_bounds__(512, 2) void k_scan2(
        const float* __restrict__ q, const bf16* __restrict__ L_in,
        const bf16* __restrict__ nUk_h, const bf16* __restrict__ nUk_l,
        const bf16* __restrict__ Kt_h, const bf16* __restrict__ Kt_l,
        const float* __restrict__ Uv_in, float* __restrict__ of) {
    __shared__ bf16 ShT_h[2][64][72], ShT_l[2][64][72], Ut_h[2][64][72], Ut_l[2][64][72];
    const int tid = threadIdx.x, lane = tid & 63, wid = tid >> 6;
    const int w = wid & 3;
    const bool SR = (wid < 4);
    const int bh = blockIdx.x, b = bh >> 4, hh = bh & 15;
    const int col0 = hh * 64;
    const int fr = lane & 15, fg = lane >> 4;

    {   // zero initial state S_0
        bf16* z0 = &ShT_h[0][0][0]; bf16* z1 = &ShT_l[0][0][0];
        for (int i = tid; i < 64 * 72; i += 512) { z0[i] = (bf16)0.f; z1[i] = (bf16)0.f; }
    }
    __syncthreads();

    auto offc = [&](int c) { return ((size_t)bh * 32 + c) * 4096; };
    auto rac  = [&](int c) { return offc(c) + (size_t)(w * 16 + fr) * 64 + fg * 8; };

    // S-role frags (current chunk)
    f32x4 Sacc[4];
    bf16x8 nkh0, nkh1, nkl0, nkl1, kth0, kth1, ktl0, ktl1;
    f32x4 uv0, uv1, uv2, uv3;
    // O-role frags (current chunk)
    bf16x8 lf0, lf1, qf0, qf1;

    if (SR) {
#pragma unroll
        for (int vt = 0; vt < 4; ++vt) Sacc[vt] = (f32x4){0, 0, 0, 0};
        size_t ra = rac(0);
        nkh0 = *(const bf16x8*)(nUk_h + ra); nkh1 = *(const bf16x8*)(nUk_h + ra + 32);
        nkl0 = *(const bf16x8*)(nUk_l + ra); nkl1 = *(const bf16x8*)(nUk_l + ra + 32);
        kth0 = *(const bf16x8*)(Kt_h + ra);  kth1 = *(const bf16x8*)(Kt_h + ra + 32);
        ktl0 = *(const bf16x8*)(Kt_l + ra);  ktl1 = *(const bf16x8*)(Kt_l + ra + 32);
        const float* up = Uv_in + offc(0) + w * 1024 + lane * 4;
        uv0 = *(const f32x4*)up;         uv1 = *(const f32x4*)(up + 256);
        uv2 = *(const f32x4*)(up + 512); uv3 = *(const f32x4*)(up + 768);
    }

    for (int c = 0; c < 32; ++c) {
        const int p = c & 1;
        // prefetch temporaries (committed at end of iteration)
        bf16x8 tnkh0, tnkh1, tnkl0, tnkl1, tkth0, tkth1, tktl0, tktl1;
        f32x4 tuv0, tuv1, tuv2, tuv3;
        bf16x8 tlf0, tlf1, tqf0, tqf1;

        if (SR) {
            if (c < 31) {   // issue next-chunk loads early
                size_t ra = rac(c + 1);
                tnkh0 = *(const bf16x8*)(nUk_h + ra); tnkh1 = *(const bf16x8*)(nUk_h + ra + 32);
                tnkl0 = *(const bf16x8*)(nUk_l + ra); tnkl1 = *(const bf16x8*)(nUk_l + ra + 32);
                tkth0 = *(const bf16x8*)(Kt_h + ra);  tkth1 = *(const bf16x8*)(Kt_h + ra + 32);
                tktl0 = *(const bf16x8*)(Kt_l + ra);  tktl1 = *(const bf16x8*)(Kt_l + ra + 32);
                const float* up = Uv_in + offc(c + 1) + w * 1024 + lane * 4;
                tuv0 = *(const f32x4*)up;         tuv1 = *(const f32x4*)(up + 256);
                tuv2 = *(const f32x4*)(up + 512); tuv3 = *(const f32x4*)(up + 768);
            }
            // m1: U_c = Uv_c + nUk_c * S_c   (reads ShT[p])
            f32x4 Uacc[4] = {uv0, uv1, uv2, uv3};
#pragma unroll
            for (int vt = 0; vt < 4; ++vt) {
                const bf16* sh0 = &ShT_h[p][vt * 16 + fr][fg * 8];
                const bf16* sl0 = &ShT_l[p][vt * 16 + fr][fg * 8];
                bf16x8 sh = *(const bf16x8*)sh0, sl = *(const bf16x8*)sl0;
                Uacc[vt] = MFMA(nkh0, sh, Uacc[vt]);
                Uacc[vt] = MFMA(nkh0, sl, Uacc[vt]);
                Uacc[vt] = MFMA(nkl0, sh, Uacc[vt]);
                sh = *(const bf16x8*)(sh0 + 32); sl = *(const bf16x8*)(sl0 + 32);
                Uacc[vt] = MFMA(nkh1, sh, Uacc[vt]);
                Uacc[vt] = MFMA(nkh1, sl, Uacc[vt]);
                Uacc[vt] = MFMA(nkl1, sh, Uacc[vt]);
            }
            // write U^T (hi/lo) to Ut[p]
#pragma unroll
            for (int vt = 0; vt < 4; ++vt) {
                int vg = vt * 16 + fr;
#pragma unroll
                for (int j = 0; j < 4; ++j) {
                    int tg = w * 16 + fg * 4 + j;
                    float u = Uacc[vt][j];
                    bf16 hhv = (bf16)u;
                    Ut_h[p][vg][tg] = hhv;
                    Ut_l[p][vg][tg] = (bf16)(u - (float)hhv);
                }
            }
        } else {
            // issue loads for chunk c (used next iteration)
            size_t ra = rac(c);
            tlf0 = *(const bf16x8*)(L_in + ra); tlf1 = *(const bf16x8*)(L_in + ra + 32);
            const float* qp = q + (size_t)(b * TT + c * 64 + w * 16 + fr) * DD + col0 + fg * 8;
            float4 qa = *(const float4*)qp,        qb = *(const float4*)(qp + 4);
            float4 qc = *(const float4*)(qp + 32), qd = *(const float4*)(qp + 36);
            tqf0[0]=(bf16)qa.x; tqf0[1]=(bf16)qa.y; tqf0[2]=(bf16)qa.z; tqf0[3]=(bf16)qa.w;
            tqf0[4]=(bf16)qb.x; tqf0[5]=(bf16)qb.y; tqf0[6]=(bf16)qb.z; tqf0[7]=(bf16)qb.w;
            tqf1[0]=(bf16)qc.x; tqf1[1]=(bf16)qc.y; tqf1[2]=(bf16)qc.z; tqf1[3]=(bf16)qc.w;
            tqf1[4]=(bf16)qd.x; tqf1[5]=(bf16)qd.y; tqf1[6]=(bf16)qd.z; tqf1[7]=(bf16)qd.w;
            if (c > 0) {
                // O_{c-1} = Q_{c-1}*S_{c-1} + L_{c-1}*U_{c-1}   (reads ShT[1-p], Ut[1-p])
                f32x4 Oacc[4];
#pragma unroll
                for (int vt = 0; vt < 4; ++vt) Oacc[vt] = (f32x4){0, 0, 0, 0};
#pragma unroll
                for (int vt = 0; vt < 4; ++vt) {
                    const bf16* so0 = &ShT_h[1 - p][vt * 16 + fr][fg * 8];
                    const bf16* uh0 = &Ut_h[1 - p][vt * 16 + fr][fg * 8];
                    bf16x8 so = *(const bf16x8*)so0, uh = *(const bf16x8*)uh0;
                    Oacc[vt] = MFMA(qf0, so, Oacc[vt]);
                    Oacc[vt] = MFMA(lf0, uh, Oacc[vt]);
                    so = *(const bf16x8*)(so0 + 32); uh = *(const bf16x8*)(uh0 + 32);
                    Oacc[vt] = MFMA(qf1, so, Oacc[vt]);
                    Oacc[vt] = MFMA(lf1, uh, Oacc[vt]);
                }
                float* ob = of + offc(c - 1) + (size_t)(w * 4) * 256 + (size_t)lane * 4;
#pragma unroll
                for (int vt = 0; vt < 4; ++vt) *(f32x4*)(ob + vt * 256) = Oacc[vt];
            }
        }
        __syncthreads();   // Ut[p] ready; O's reads of ShT[1-p]/Ut[1-p] done
        if (SR) {
            // m2S: S_{c+1} = S_c + Kt_c * U_c   (reads Ut[p], writes ShT[1-p])
#pragma unroll
            for (int vt = 0; vt < 4; ++vt) {
                const bf16* uh0 = &Ut_h[p][vt * 16 + fr][fg * 8];
                const bf16* ul0 = &Ut_l[p][vt * 16 + fr][fg * 8];
                bf16x8 uh = *(const bf16x8*)uh0, ul = *(const bf16x8*)ul0;
                Sacc[vt] = MFMA(kth0, uh, Sacc[vt]);
                Sacc[vt] = MFMA(kth0, ul, Sacc[vt]);
                Sacc[vt] = MFMA(ktl0, uh, Sacc[vt]);
                uh = *(const bf16x8*)(uh0 + 32); ul = *(const bf16x8*)(ul0 + 32);
                Sacc[vt] = MFMA(kth1, uh, Sacc[vt]);
                Sacc[vt] = MFMA(kth1, ul, Sacc[vt]);
                Sacc[vt] = MFMA(ktl1, uh, Sacc[vt]);
            }
            if (c < 31) {
#pragma unroll
                for (int vt = 0; vt < 4; ++vt) {
                    int vg = vt * 16 + fr;
#pragma unroll
                    for (int j = 0; j < 4; ++j) {
                        int tg = w * 16 + fg * 4 + j;
                        float s = Sacc[vt][j];
                        bf16 hhv = (bf16)s;
                        ShT_h[1 - p][vg][tg] = hhv;
                        ShT_l[1 - p][vg][tg] = (bf16)(s - (float)hhv);
                    }
                }
                // commit prefetched frags
                nkh0 = tnkh0; nkh1 = tnkh1; nkl0 = tnkl0; nkl1 = tnkl1;
                kth0 = tkth0; kth1 = tkth1; ktl0 = tktl0; ktl1 = tktl1;
                uv0 = tuv0; uv1 = tuv1; uv2 = tuv2; uv3 = tuv3;
            }
        } else {
            lf0 = tlf0; lf1 = tlf1; qf0 = tqf0; qf1 = tqf1;
        }
        __syncthreads();   // ShT[1-p] ready for next m1
    }
    // epilogue: O for chunk 31 (reads ShT[1], Ut[1])
    if (!SR) {
        f32x4 Oacc[4];
#pragma unroll
        for (int vt = 0; vt < 4; ++vt) Oacc[vt] = (f32x4){0, 0, 0, 0};
#pragma unroll
        for (int vt = 0; vt < 4; ++vt) {
            const bf16* so0 = &ShT_h[1][vt * 16 + fr][fg * 8];
            const bf16* uh0 = &Ut_h[1][vt * 16 + fr][fg * 8];
            bf16x8 so = *(const bf16x8*)so0, uh = *(const bf16x8*)uh0;
            Oacc[vt] = MFMA(qf0, so, Oacc[vt]);
            Oacc[vt] = MFMA(lf0, uh, Oacc[vt]);
            so = *(const bf16x8*)(so0 + 32); uh = *(const bf16x8*)(uh0 + 32);
            Oacc[vt] = MFMA(qf1, so, Oacc[vt]);
            Oacc[vt] = MFMA(lf1, uh, Oacc[vt]);
        }
        float* ob = of + offc(31) + (size_t)(w * 4) * 256 + (size_t)lane * 4;
#pragma unroll
        for (int vt = 0; vt < 4; ++vt) *(f32x4*)(ob + vt * 256) = Oacc[vt];
    }
}

// ---------------- per-head RMSNorm * o_gamma, cast bf16 (row-major o, fallback) ----------------
__global__ __launch_bounds__(256) void k_rms(const float* __restrict__ o, const float* __restrict__ gm,
                                             bf16* __restrict__ obf) {
    size_t row = (size_t)blockIdx.x * 4 + (threadIdx.x >> 6);
    int lane = threadIdx.x & 63;
    int h = (int)(row & 15);
    float x = o[row * 64 + lane];
    float ss = x * x;
#pragma unroll
    for (int m = 1; m < 64; m <<= 1) ss += __shfl_xor(ss, m);
    float y = x * rsqrtf(ss * (1.f / 64.f) + 1e-6f) * gm[h * 64 + lane];
    obf[row * 64 + lane] = (bf16)y;
}

// ---------------- per-head RMSNorm from FRAGMENT-ORDERED o (fast path) ----------------
// thread (w,lane=fg*16+fr): for vt, f32x4 at off+((w*4+vt)*64+lane)*4 = col vt*16+fr,
// rows w*16+fg*4+{0..3}. Reduce over fr (16-lane xor) after local vt sum -> 4 row-sums.
__global__ __launch_bounds__(256) void k_rms2(const float* __restrict__ of, const float* __restrict__ gm,
                                              bf16* __restrict__ obf) {
    const int c = blockIdx.x, bh = blockIdx.y;
    const int b = bh >> 4, h = bh & 15;
    const int tid = threadIdx.x, lane = tid & 63, w = tid >> 6;
    const int fr = lane & 15, fg = lane >> 4;
    const size_t off = ((size_t)bh * 32 + c) * 4096;
    f32x4 val[4];
    float ss0 = 0.f, ss1 = 0.f, ss2 = 0.f, ss3 = 0.f;
#pragma unroll
    for (int vt = 0; vt < 4; ++vt) {
        val[vt] = *(const f32x4*)(of + off + (size_t)((w * 4 + vt) * 64 + lane) * 4);
        ss0 += val[vt][0] * val[vt][0];
        ss1 += val[vt][1] * val[vt][1];
        ss2 += val[vt][2] * val[vt][2];
        ss3 += val[vt][3] * val[vt][3];
    }
#pragma unroll
    for (int m = 1; m < 16; m <<= 1) {
        ss0 += __shfl_xor(ss0, m); ss1 += __shfl_xor(ss1, m);
        ss2 += __shfl_xor(ss2, m); ss3 += __shfl_xor(ss3, m);
    }
    float r0 = rsqrtf(ss0 * (1.f / 64.f) + 1e-6f);
    float r1 = rsqrtf(ss1 * (1.f / 64.f) + 1e-6f);
    float r2 = rsqrtf(ss2 * (1.f / 64.f) + 1e-6f);
    float r3 = rsqrtf(ss3 * (1.f / 64.f) + 1e-6f);
    const int row0 = b * TT + c * 64 + w * 16 + fg * 4;
#pragma unroll
    for (int vt = 0; vt < 4; ++vt) {
        int vg = vt * 16 + fr;
        float g = gm[h * 64 + vg];
        size_t base = (size_t)row0 * DD + h * 64 + vg;
        obf[base]          = (bf16)(val[vt][0] * r0 * g);
        obf[base + DD]     = (bf16)(val[vt][1] * r1 * g);
        obf[base + 2 * DD] = (bf16)(val[vt][2] * r2 * g);
        obf[base + 3 * DD] = (bf16)(val[vt][3] * r3 * g);
    }
}

// ---------------- residual + LayerNorm ----------------
__global__ __launch_bounds__(256) void k_ln(const float* __restrict__ yp, const float* __restrict__ x,
                                            const float* __restrict__ g, const float* __restrict__ bb,
                                            float* __restrict__ outp) {
    const int row = blockIdx.x;
    const int tid = threadIdx.x;
    __shared__ float red[8];
    const size_t base = (size_t)row * DD + tid * 4;
    float4 a  = *(const float4*)(yp + base);
    float4 b4 = *(const float4*)(x + base);
    float y0 = a.x + b4.x, y1 = a.y + b4.y, y2 = a.z + b4.z, y3 = a.w + b4.w;
    float s = (y0 + y1) + (y2 + y3);
#pragma unroll
    for (int m = 1; m < 64; m <<= 1) s += __shfl_xor(s, m);
    if ((tid & 63) == 0) red[tid >> 6] = s;
    __syncthreads();
    float mu = (red[0] + red[1] + red[2] + red[3]) * (1.f / (float)DD);
    float d0 = y0 - mu, d1 = y1 - mu, d2 = y2 - mu, d3 = y3 - mu;
    float sq = (d0 * d0 + d1 * d1) + (d2 * d2 + d3 * d3);
#pragma unroll
    for (int m = 1; m < 64; m <<= 1) sq += __shfl_xor(sq, m);
    if ((tid & 63) == 0) red[4 + (tid >> 6)] = sq;
    __syncthreads();
    float var = (red[4] + red[5] + red[6] + red[7]) * (1.f / (float)DD);
    float inv = rsqrtf(var + 1e-5f);
    const int c = tid * 4;
    float4 gg = *(const float4*)(g + c);
    float4 bv = *(const float4*)(bb + c);
    float4 r;
    r.x = d0 * inv * gg.x + bv.x;
    r.y = d1 * inv * gg.y + bv.y;
    r.z = d2 * inv * gg.z + bv.z;
    r.w = d3 * inv * gg.w + bv.w;
    *(float4*)(outp + base) = r;
}

// ---------------- launcher ----------------
extern "C" void kernel_launch(void* const* d_in, const int* in_sizes, int n_in,
                              void* d_out, int out_size, void* d_ws, size_t ws_size,
                              hipStream_t stream) {
    (void)in_sizes; (void)n_in; (void)out_size;
    if (ws_size < ((size_t)81 << 20)) return;
    const bool fast = ws_size >= ((size_t)137 << 20);

    const float* x   = (const float*)d_in[0];
    const float* Wq  = (const float*)d_in[1];
    const float* Wk  = (const float*)d_in[2];
    const float* Wv  = (const float*)d_in[3];
    const float* Wb  = (const float*)d_in[4];
    const float* gma = (const float*)d_in[5];
    const float* Wo  = (const float*)d_in[6];
    const float* lng = (const float*)d_in[7];
    const float* lnb = (const float*)d_in[8];
    float* outp = (float*)d_out;

    char* ws = (char*)d_ws;
    bf16*  xb    = (bf16*)(ws);                         // 8 MiB
    bf16*  WqT   = (bf16*)(ws + ((size_t)8  << 20));    // 2 MiB each
    bf16*  WoT   = (bf16*)(ws + ((size_t)14 << 20));
    float* q     = (float*)(ws + ((size_t)16 << 20));
    float* k     = (float*)(ws + ((size_t)32 << 20));
    float* v     = (float*)(ws + ((size_t)48 << 20));
    float* beta  = (float*)(ws + ((size_t)64 << 20));
    bf16*  wf    = (bf16*)(ws + ((size_t)64 << 20) + (1 << 19));  // 32 KiB frag-ordered Wb
    float* o     = (float*)(ws + ((size_t)65 << 20));
    bf16*  obf   = (bf16*)(ws);                         // reuse xb
    float* yproj = (float*)(ws + ((size_t)16 << 20));   // reuse q
    // chunked-scan scratch (fast path)
    bf16*  Lbf   = (bf16*)(ws + ((size_t)81  << 20));   // 8 MiB
    bf16*  nUk_h = (bf16*)(ws + ((size_t)89  << 20));
    bf16*  nUk_l = (bf16*)(ws + ((size_t)97  << 20));
    bf16*  Kt_h  = (bf16*)(ws + ((size_t)105 << 20));
    bf16*  Kt_l  = (bf16*)(ws + ((size_t)113 << 20));
    float* Uv    = (float*)(ws + ((size_t)121 << 20));  // 16 MiB

    bf16* WkT = WqT + (size_t)DD * DD;
    bf16* WvT = WkT + (size_t)DD * DD;

    k_wbfrag<<<8, 256, 0, stream>>>(Wb, wf);
    k_cvt<<<2048, 256, 0, stream>>>(x, xb);
    dim3 tg(16, 16);
    k_transpose_cvt<<<tg, 256, 0, stream>>>(Wq, WqT);
    k_transpose_cvt<<<tg, 256, 0, stream>>>(Wk, WkT);
    k_transpose_cvt<<<tg, 256, 0, stream>>>(Wv, WvT);
    k_transpose_cvt<<<tg, 256, 0, stream>>>(Wo, WoT);
    k_gemm_qkv<<<dim3(32, 8, 3), 256, 0, stream>>>(xb, WqT, q);
    k_beta2<<<256, 64, 0, stream>>>(xb, wf, beta);
    k_actnorm<<<16384, 256, 0, stream>>>(q);
    k_actnorm<<<16384, 256, 0, stream>>>(k);
    if (fast) {
        k_prep<<<dim3(32, 32), 256, 0, stream>>>(q, k, v, beta, Lbf, nUk_h, nUk_l, Kt_h, Kt_l, Uv);
        k_scan2<<<32, 512, 0, stream>>>(q, Lbf, nUk_h, nUk_l, Kt_h, Kt_l, Uv, o);
        k_rms2<<<dim3(32, 32), 256, 0, stream>>>(o, gma, obf);
    } else {
        k_scan<<<32, 256, 0, stream>>>(q, k, v, beta, o);
        k_rms<<<16384, 256, 0, stream>>>(o, gma, obf);
    }
    k_gemm<<<dim3(32, 8), 256, 0, stream>>>(obf, WoT, yproj);
    k_ln<<<4096, 256, 0, stream>>>(yproj, x, lng, lnb, outp);
}

// Round 11
// 326.921 us; speedup vs baseline: 1.0610x; 1.0610x over previous
//
#include <hip/hip_runtime.h>
#include <hip/hip_bf16.h>
#include <cstdint>

#define BB 2
#define TT 2048
#define DD 1024
#define HH 16
#define DH 64
#define MM (BB*TT)      // 4096 rows
constexpr int KDIM = 1024;
constexpr int NDIM = 1024;

typedef __bf16 bf16;
typedef __attribute__((ext_vector_type(8))) __bf16 bf16x8;
typedef __attribute__((ext_vector_type(4))) float f32x4;

#define MFMA(a,b,c) __builtin_amdgcn_mfma_f32_16x16x32_bf16((a),(b),(c),0,0,0)

// ---------------- elementwise: f32 -> bf16 cast (x -> xb) ----------------
__global__ __launch_bounds__(256) void k_cvt(const float* __restrict__ in, bf16* __restrict__ outp) {
    size_t i = ((size_t)blockIdx.x * 256 + threadIdx.x) * 8;
    float4 a = *(const float4*)(in + i);
    float4 b = *(const float4*)(in + i + 4);
    bf16x8 r;
    r[0] = (bf16)a.x; r[1] = (bf16)a.y; r[2] = (bf16)a.z; r[3] = (bf16)a.w;
    r[4] = (bf16)b.x; r[5] = (bf16)b.y; r[6] = (bf16)b.z; r[7] = (bf16)b.w;
    *(bf16x8*)(outp + i) = r;
}

// ---------------- transpose + cast x4: W (K x N) f32 -> W^T (N x K) bf16, z picks tensor ----
__global__ __launch_bounds__(256) void k_transpose_cvt4(
        const float* __restrict__ i0, const float* __restrict__ i1,
        const float* __restrict__ i2, const float* __restrict__ i3,
        bf16* __restrict__ o0, bf16* __restrict__ o1,
        bf16* __restrict__ o2, bf16* __restrict__ o3) {
    __shared__ float tile[64][65];
    const float* in; bf16* outp;
    switch (blockIdx.z) {
        case 0:  in = i0; outp = o0; break;
        case 1:  in = i1; outp = o1; break;
        case 2:  in = i2; outp = o2; break;
        default: in = i3; outp = o3; break;
    }
    const int tx = threadIdx.x & 63;
    const int ty = threadIdx.x >> 6;
    const int r0 = blockIdx.y * 64, c0 = blockIdx.x * 64;
#pragma unroll
    for (int i = 0; i < 16; ++i) {
        int rr = ty * 16 + i;
        tile[rr][tx] = in[(size_t)(r0 + rr) * 1024 + c0 + tx];
    }
    __syncthreads();
#pragma unroll
    for (int i = 0; i < 16; ++i) {
        int rr = ty * 16 + i;
        outp[(size_t)(c0 + rr) * 1024 + r0 + tx] = (bf16)tile[tx][rr];
    }
}

// ---------------- GEMM: A (M x K, bf16 rm) @ Bt (N x K, bf16 rm) -> C f32 (bf16-rounded) ----
#define BM 128
#define BN 128
#define BKT 64

__device__ __forceinline__ void gemm_core(const bf16* __restrict__ A, const bf16* __restrict__ Bt,
                                          float* __restrict__ Cc) {
    __shared__ __align__(16) bf16 As[BM * BKT];
    __shared__ __align__(16) bf16 Bs[BN * BKT];
    const int tid  = threadIdx.x;
    const int lane = tid & 63;
    const int w    = tid >> 6;
    const int wr   = w >> 1, wc = w & 1;
    const int bm   = blockIdx.x * BM;
    const int bn   = blockIdx.y * BN;

    f32x4 acc[4][4];
#pragma unroll
    for (int m_ = 0; m_ < 4; ++m_)
#pragma unroll
        for (int n = 0; n < 4; ++n) acc[m_][n] = (f32x4){0.f, 0.f, 0.f, 0.f};

    const int srow = tid >> 3;
    const int sc   = tid & 7;
    const int sp   = sc ^ (srow & 7);
    const int fr   = lane & 15;
    const int fg   = lane >> 4;

    const bf16* Ap = A  + (size_t)(bm + srow) * KDIM + sc * 8;
    const bf16* Bp = Bt + (size_t)(bn + srow) * KDIM + sc * 8;

    for (int kt = 0; kt < KDIM; kt += BKT) {
        bf16x8 ar[4], br[4];
#pragma unroll
        for (int i = 0; i < 4; ++i) {
            ar[i] = *(const bf16x8*)(Ap + (size_t)i * 32 * KDIM + kt);
            br[i] = *(const bf16x8*)(Bp + (size_t)i * 32 * KDIM + kt);
        }
        __syncthreads();
#pragma unroll
        for (int i = 0; i < 4; ++i) {
            *(bf16x8*)(As + (i * 32 + srow) * BKT + sp * 8) = ar[i];
            *(bf16x8*)(Bs + (i * 32 + srow) * BKT + sp * 8) = br[i];
        }
        __syncthreads();
#pragma unroll
        for (int s = 0; s < 2; ++s) {
            bf16x8 af[4], bfv[4];
#pragma unroll
            for (int m_ = 0; m_ < 4; ++m_) {
                int row = wr * 64 + m_ * 16 + fr;
                int p   = (s * 4 + fg) ^ (row & 7);
                af[m_] = *(const bf16x8*)(As + row * BKT + p * 8);
            }
#pragma unroll
            for (int n = 0; n < 4; ++n) {
                int row = wc * 64 + n * 16 + fr;
                int p   = (s * 4 + fg) ^ (row & 7);
                bfv[n] = *(const bf16x8*)(Bs + row * BKT + p * 8);
            }
#pragma unroll
            for (int m_ = 0; m_ < 4; ++m_)
#pragma unroll
                for (int n = 0; n < 4; ++n)
                    acc[m_][n] = MFMA(af[m_], bfv[n], acc[m_][n]);
        }
    }
#pragma unroll
    for (int m_ = 0; m_ < 4; ++m_) {
        int row0 = bm + wr * 64 + m_ * 16 + fg * 4;
#pragma unroll
        for (int j = 0; j < 4; ++j)
#pragma unroll
            for (int n = 0; n < 4; ++n) {
                int col = bn + wc * 64 + n * 16 + fr;
                Cc[(size_t)(row0 + j) * NDIM + col] = (float)((bf16)acc[m_][n][j]);
            }
    }
}

__global__ __launch_bounds__(256) void k_gemm(const bf16* __restrict__ A, const bf16* __restrict__ Bt,
                                              float* __restrict__ Cc) {
    gemm_core(A, Bt, Cc);
}

__global__ __launch_bounds__(256) void k_gemm_qkv(const bf16* __restrict__ A, const bf16* __restrict__ WtBase,
                                                  float* __restrict__ outBase) {
    int z = blockIdx.z;
    gemm_core(A, WtBase + (size_t)z * (DD * DD), outBase + (size_t)z * ((size_t)MM * DD));
}

// ---------------- Wb (1024x16 f32) -> fragment-ordered bf16 [s][lane][e] ----------------
__global__ __launch_bounds__(256) void k_wbfrag(const float* __restrict__ Wb, bf16* __restrict__ wf) {
    int i = blockIdx.x * 256 + threadIdx.x;   // 2048 slots (32 s-steps x 64 lanes)
    int s = i >> 6, l = i & 63;
    int h = l & 15, kb = (l >> 4) * 8;
    bf16x8 r;
#pragma unroll
    for (int e = 0; e < 8; ++e) r[e] = (bf16)Wb[(size_t)(s * 32 + kb + e) * HH + h];
    *(bf16x8*)(wf + (size_t)i * 8) = r;
}

// ---------------- beta = 2*sigmoid(bf16round(xb @ Wb_bf16)) via MFMA ----------------
__global__ __launch_bounds__(64) void k_beta2(const bf16* __restrict__ xb, const bf16* __restrict__ wf,
                                              float* __restrict__ beta) {
    const int lane = threadIdx.x;
    const int fr = lane & 15, fg = lane >> 4;
    const int tile = blockIdx.x;
    const bf16* ap = xb + (size_t)(tile * 16 + fr) * DD + fg * 8;
    f32x4 acc = (f32x4){0.f, 0.f, 0.f, 0.f};
#pragma unroll
    for (int s = 0; s < 32; ++s) {
        bf16x8 a = *(const bf16x8*)(ap + s * 32);
        bf16x8 b = *(const bf16x8*)(wf + ((size_t)s * 64 + lane) * 8);
        acc = MFMA(a, b, acc);
    }
#pragma unroll
    for (int j = 0; j < 4; ++j) {
        float rr = (float)((bf16)acc[j]);       // jnp bf16 matmul rounds before astype(f32)
        beta[(size_t)(tile * 16 + fg * 4 + j) * HH + fr] = 2.f / (1.f + expf(-rr));
    }
}

// ---------------- silu + per-head l2norm, in place (q and k contiguous: one launch) ----------------
__global__ __launch_bounds__(256) void k_actnorm(float* __restrict__ a) {
    size_t row = (size_t)blockIdx.x * 4 + (threadIdx.x >> 6);
    int lane = threadIdx.x & 63;
    float x = a[row * 64 + lane];
    float e = x / (1.f + expf(-x));
    float ss = e * e;
#pragma unroll
    for (int m = 1; m < 64; m <<= 1) ss += __shfl_xor(ss, m);
    a[row * 64 + lane] = e * rsqrtf(ss + 1e-6f);
}

// ---------------- OLD sequential delta-rule scan (fallback if ws too small) ----------------
__global__ __launch_bounds__(256) void k_scan(const float* __restrict__ Qv, const float* __restrict__ Kv,
                                              const float* __restrict__ Vv, const float* __restrict__ Bv,
                                              float* __restrict__ Ov) {
    const int bh = blockIdx.x;
    const int b = bh >> 4, h = bh & 15;
    const int tid = threadIdx.x;
    const int r   = tid >> 2;
    const int seg = tid & 3;
    float S[16];
#pragma unroll
    for (int j = 0; j < 16; ++j) S[j] = 0.f;
    const size_t base = ((size_t)b * TT) * DD + (size_t)h * DH;
    const float* kp = Kv + base + seg * 16;
    const float* qp = Qv + base + seg * 16;
    const float* vp = Vv + base + r;
    const float* bp = Bv + ((size_t)b * TT) * HH + h;
    float* op = Ov + base + r;

    float4 k0, k1, k2, k3, q0, q1, q2, q3;
    float vv, bt;
    k0 = *(const float4*)(kp + 0);  k1 = *(const float4*)(kp + 4);
    k2 = *(const float4*)(kp + 8);  k3 = *(const float4*)(kp + 12);
    q0 = *(const float4*)(qp + 0);  q1 = *(const float4*)(qp + 4);
    q2 = *(const float4*)(qp + 8);  q3 = *(const float4*)(qp + 12);
    vv = *vp; bt = *bp;

    for (int t = 0; t < TT; ++t) {
        float4 nk0, nk1, nk2, nk3, nq0, nq1, nq2, nq3;
        float nvv = 0.f, nbt = 0.f;
        if (t + 1 < TT) {
            const float* kn = kp + (size_t)(t + 1) * DD;
            const float* qn = qp + (size_t)(t + 1) * DD;
            nk0 = *(const float4*)(kn + 0);  nk1 = *(const float4*)(kn + 4);
            nk2 = *(const float4*)(kn + 8);  nk3 = *(const float4*)(kn + 12);
            nq0 = *(const float4*)(qn + 0);  nq1 = *(const float4*)(qn + 4);
            nq2 = *(const float4*)(qn + 8);  nq3 = *(const float4*)(qn + 12);
            nvv = vp[(size_t)(t + 1) * DD];
            nbt = bp[(size_t)(t + 1) * HH];
        }
        float a0, a1, a2, a3;
        a0 = S[0] * k0.x;  a1 = S[1] * k0.y;  a2 = S[2] * k0.z;  a3 = S[3] * k0.w;
        a0 = fmaf(S[4],  k1.x, a0); a1 = fmaf(S[5],  k1.y, a1); a2 = fmaf(S[6],  k1.z, a2); a3 = fmaf(S[7],  k1.w, a3);
        a0 = fmaf(S[8],  k2.x, a0); a1 = fmaf(S[9],  k2.y, a1); a2 = fmaf(S[10], k2.z, a2); a3 = fmaf(S[11], k2.w, a3);
        a0 = fmaf(S[12], k3.x, a0); a1 = fmaf(S[13], k3.y, a1); a2 = fmaf(S[14], k3.z, a2); a3 = fmaf(S[15], k3.w, a3);
        float sk = (a0 + a1) + (a2 + a3);
        sk += __shfl_xor(sk, 1); sk += __shfl_xor(sk, 2);
        const float wgt = bt * (vv - sk);
        float o0, o1, o2, o3;
        S[0]  = fmaf(wgt, k0.x, S[0]);  o0 = S[0] * q0.x;
        S[1]  = fmaf(wgt, k0.y, S[1]);  o1 = S[1] * q0.y;
        S[2]  = fmaf(wgt, k0.z, S[2]);  o2 = S[2] * q0.z;
        S[3]  = fmaf(wgt, k0.w, S[3]);  o3 = S[3] * q0.w;
        S[4]  = fmaf(wgt, k1.x, S[4]);  o0 = fmaf(S[4],  q1.x, o0);
        S[5]  = fmaf(wgt, k1.y, S[5]);  o1 = fmaf(S[5],  q1.y, o1);
        S[6]  = fmaf(wgt, k1.z, S[6]);  o2 = fmaf(S[6],  q1.z, o2);
        S[7]  = fmaf(wgt, k1.w, S[7]);  o3 = fmaf(S[7],  q1.w, o3);
        S[8]  = fmaf(wgt, k2.x, S[8]);  o0 = fmaf(S[8],  q2.x, o0);
        S[9]  = fmaf(wgt, k2.y, S[9]);  o1 = fmaf(S[9],  q2.y, o1);
        S[10] = fmaf(wgt, k2.z, S[10]); o2 = fmaf(S[10], q2.z, o2);
        S[11] = fmaf(wgt, k2.w, S[11]); o3 = fmaf(S[11], q2.w, o3);
        S[12] = fmaf(wgt, k3.x, S[12]); o0 = fmaf(S[12], q3.x, o0);
        S[13] = fmaf(wgt, k3.y, S[13]); o1 = fmaf(S[13], q3.y, o1);
        S[14] = fmaf(wgt, k3.z, S[14]); o2 = fmaf(S[14], q3.z, o2);
        S[15] = fmaf(wgt, k3.w, S[15]); o3 = fmaf(S[15], q3.w, o3);
        float oo = (o0 + o1) + (o2 + o3);
        oo += __shfl_xor(oo, 1); oo += __shfl_xor(oo, 2);
        if (seg == 0) op[(size_t)t * DD] = oo;
        k0 = nk0; k1 = nk1; k2 = nk2; k3 = nk3;
        q0 = nq0; q1 = nq1; q2 = nq2; q3 = nq3;
        vv = nvv; bt = nbt;
    }
}

// =================== CHUNKED WY SCAN ===================
// Chunk C=64. k_prep (parallel): A = tril(beta*K.K^T), solve (I+A)[Uv|Uk] = diag(beta)[V|K],
// L = tril(Q.K^T), Qf = bf16 Q fragments. k_scan2 (sequential, 4 waves, S/O interleaved,
// per-CU BW-bound -> minimize bytes):
//   U  = Uv - Uk * S0          (bf16x2 MFMA, acc init = Uv fp32)
//   O  = Q*S0 + L*U -> fused per-head RMSNorm -> obf  (plain bf16 MFMA)
//   S1 = S0 + K^T * U          (bf16x2 MFMA)

__device__ __forceinline__ int uv_idx(int t, int vv) {
    // fragment-order so phase2 wave w loads f32x4 at ((w*4+vt)*64 + lane)*4
    return (((t >> 4) * 4 + (vv >> 4)) * 64 + (((t >> 2) & 3) * 16 + (vv & 15))) * 4 + (t & 3);
}

__global__ __launch_bounds__(256, 3) void k_prep(
        const float* __restrict__ q, const float* __restrict__ k, const float* __restrict__ v,
        const float* __restrict__ beta,
        bf16* __restrict__ L_out, bf16* __restrict__ nUk_h, bf16* __restrict__ nUk_l,
        bf16* __restrict__ Kt_h, bf16* __restrict__ Kt_l, float* __restrict__ Uv_out,
        bf16* __restrict__ Qf) {
    __shared__ float Ash[64][65];
    __shared__ bf16 Khi[64][72], Klo[64][72];
    __shared__ float bsh[64];

    const int tid = threadIdx.x;
    const int c = blockIdx.x, bh = blockIdx.y, b = bh >> 4, h = bh & 15;
    const int row0 = b * TT + c * 64, col0 = h * 64;
    const size_t off = ((size_t)bh * 32 + c) * 4096;
    const int lane = tid & 63, w = tid >> 6;
    const int fr = lane & 15, fg = lane >> 4;

    // ---- early global loads ----
    const int cslice = (w & 1) * 32;
    const float* rp = ((w >= 2) ? k : v) + (size_t)(row0 + lane) * DD + col0 + cslice;
    float4 rv[8];
#pragma unroll
    for (int a = 0; a < 8; ++a) rv[a] = *(const float4*)(rp + a * 4);
    const float* qfp = q + (size_t)(row0 + w * 16 + fr) * DD + col0 + fg * 8;
    float4 qa = *(const float4*)qfp, qb = *(const float4*)(qfp + 4);
    float4 qc = *(const float4*)(qfp + 32), qd = *(const float4*)(qfp + 36);
    const int tr = tid >> 2, cs = (tid & 3) * 16;
    float4 kv[4];
    const size_t rb = (size_t)(row0 + tr) * DD + col0 + cs;
#pragma unroll
    for (int j = 0; j < 4; ++j) kv[j] = *(const float4*)(k + rb + j * 4);

    if (tid < 64) bsh[tid] = beta[(size_t)(row0 + tid) * HH + h];
#pragma unroll
    for (int j = 0; j < 4; ++j) {
        int cb = cs + j * 4;
        float a0 = kv[j].x, a1 = kv[j].y, a2 = kv[j].z, a3 = kv[j].w;
        bf16 h0 = (bf16)a0, h1 = (bf16)a1, h2 = (bf16)a2, h3 = (bf16)a3;
        Khi[tr][cb] = h0; Khi[tr][cb+1] = h1; Khi[tr][cb+2] = h2; Khi[tr][cb+3] = h3;
        Klo[tr][cb]   = (bf16)(a0 - (float)h0);
        Klo[tr][cb+1] = (bf16)(a1 - (float)h1);
        Klo[tr][cb+2] = (bf16)(a2 - (float)h2);
        Klo[tr][cb+3] = (bf16)(a3 - (float)h3);
    }
    __syncthreads();

    // ---- MFMA: A_raw = K.K^T (bf16x2), L = tril(Q.K^T); store Qf fragments ----
    {
        bf16x8 aqh0, aqh1;
        aqh0[0]=(bf16)qa.x; aqh0[1]=(bf16)qa.y; aqh0[2]=(bf16)qa.z; aqh0[3]=(bf16)qa.w;
        aqh0[4]=(bf16)qb.x; aqh0[5]=(bf16)qb.y; aqh0[6]=(bf16)qb.z; aqh0[7]=(bf16)qb.w;
        aqh1[0]=(bf16)qc.x; aqh1[1]=(bf16)qc.y; aqh1[2]=(bf16)qc.z; aqh1[3]=(bf16)qc.w;
        aqh1[4]=(bf16)qd.x; aqh1[5]=(bf16)qd.y; aqh1[6]=(bf16)qd.z; aqh1[7]=(bf16)qd.w;
        {   // Qf fragment store (same values scan2 previously built in-loop)
            const size_t ra = off + (size_t)(w * 16 + fr) * 64 + fg * 8;
            *(bf16x8*)(Qf + ra) = aqh0;
            *(bf16x8*)(Qf + ra + 32) = aqh1;
        }
        f32x4 accA[4], accL[4];
#pragma unroll
        for (int it = 0; it < 4; ++it) { accA[it] = (f32x4){0,0,0,0}; accL[it] = (f32x4){0,0,0,0}; }
        bf16x8 akh0 = *(const bf16x8*)&Khi[w*16+fr][fg*8];
        bf16x8 akh1 = *(const bf16x8*)&Khi[w*16+fr][fg*8+32];
        bf16x8 akl0 = *(const bf16x8*)&Klo[w*16+fr][fg*8];
        bf16x8 akl1 = *(const bf16x8*)&Klo[w*16+fr][fg*8+32];
#pragma unroll
        for (int it = 0; it < 4; ++it) {
            bf16x8 bh0 = *(const bf16x8*)&Khi[it*16+fr][fg*8];
            bf16x8 bl0 = *(const bf16x8*)&Klo[it*16+fr][fg*8];
            accA[it] = MFMA(akh0, bh0, accA[it]);
            accA[it] = MFMA(akh0, bl0, accA[it]);
            accA[it] = MFMA(akl0, bh0, accA[it]);
            accL[it] = MFMA(aqh0, bh0, accL[it]);
            bf16x8 bh1 = *(const bf16x8*)&Khi[it*16+fr][fg*8+32];
            bf16x8 bl1 = *(const bf16x8*)&Klo[it*16+fr][fg*8+32];
            accA[it] = MFMA(akh1, bh1, accA[it]);
            accA[it] = MFMA(akh1, bl1, accA[it]);
            accA[it] = MFMA(akl1, bh1, accA[it]);
            accL[it] = MFMA(aqh1, bh1, accL[it]);
        }
#pragma unroll
        for (int it = 0; it < 4; ++it)
#pragma unroll
            for (int j = 0; j < 4; ++j) {
                int tg = w * 16 + fg * 4 + j, ig = it * 16 + fr;
                Ash[tg][ig] = (ig < tg) ? bsh[tg] * accA[it][j] : 0.f;
                L_out[off + tg * 64 + ig] = (ig <= tg) ? (bf16)accL[it][j] : (bf16)0.f;
            }
    }
    __syncthreads();

    // ---- barrier-free substitution: X[t][col] in registers, lane=row ----
    float bt = bsh[lane];
    float X[32];
#pragma unroll
    for (int a = 0; a < 8; ++a) {
        X[a*4+0] = bt * rv[a].x; X[a*4+1] = bt * rv[a].y;
        X[a*4+2] = bt * rv[a].z; X[a*4+3] = bt * rv[a].w;
    }
#pragma unroll 1
    for (int i = 0; i < 63; ++i) {
        float a = Ash[lane][i];          // conflict-free: stride-65, 2 lanes/bank
#pragma unroll
        for (int j = 0; j < 32; ++j) {
            float s = __uint_as_float(__builtin_amdgcn_readlane(__float_as_uint(X[j]), i));
            X[j] = fmaf(-a, s, X[j]);    // a==0 for i>=lane (zero-padded A)
        }
    }

    // ---- outputs ----
    if (w < 2) {                         // V columns -> Uv (fp32, fragment order)
#pragma unroll
        for (int j = 0; j < 32; ++j)
            Uv_out[off + uv_idx(lane, cslice + j)] = X[j];
    } else {                             // K columns -> -Uk hi/lo
#pragma unroll
        for (int g = 0; g < 4; ++g) {
            bf16x8 hi8, lo8;
#pragma unroll
            for (int e = 0; e < 8; ++e) {
                float nk = -X[g*8+e];
                bf16 nh = (bf16)nk;
                hi8[e] = nh;
                lo8[e] = (bf16)(nk - (float)nh);
            }
            *(bf16x8*)(nUk_h + off + (size_t)lane*64 + cslice + g*8) = hi8;
            *(bf16x8*)(nUk_l + off + (size_t)lane*64 + cslice + g*8) = lo8;
        }
    }
#pragma unroll
    for (int j = 0; j < 16; ++j) {
        int vc = cs + j;
        Kt_h[off + (size_t)tr*64 + vc] = Khi[vc][tr];
        Kt_l[off + (size_t)tr*64 + vc] = Klo[vc][tr];
    }
}

struct Frag {
    bf16x8 nkh0, nkh1, nkl0, nkl1;
    bf16x8 kth0, kth1, ktl0, ktl1;
    bf16x8 lf0, lf1, qf0, qf1;
    f32x4 uv0, uv1, uv2, uv3;
};

__device__ __forceinline__ void load_frags(Frag& F,
        const bf16* __restrict__ nUk_h, const bf16* __restrict__ nUk_l,
        const bf16* __restrict__ Kt_h, const bf16* __restrict__ Kt_l,
        const bf16* __restrict__ L_in, const bf16* __restrict__ Qf,
        const float* __restrict__ Uv_in, size_t off, int w, int lane) {
    const int fr = lane & 15, fg = lane >> 4;
    const size_t ra = off + (size_t)(w * 16 + fr) * 64 + fg * 8;
    F.nkh0 = *(const bf16x8*)(nUk_h + ra); F.nkh1 = *(const bf16x8*)(nUk_h + ra + 32);
    F.nkl0 = *(const bf16x8*)(nUk_l + ra); F.nkl1 = *(const bf16x8*)(nUk_l + ra + 32);
    F.kth0 = *(const bf16x8*)(Kt_h + ra);  F.kth1 = *(const bf16x8*)(Kt_h + ra + 32);
    F.ktl0 = *(const bf16x8*)(Kt_l + ra);  F.ktl1 = *(const bf16x8*)(Kt_l + ra + 32);
    F.lf0  = *(const bf16x8*)(L_in + ra);  F.lf1  = *(const bf16x8*)(L_in + ra + 32);
    F.qf0  = *(const bf16x8*)(Qf + ra);    F.qf1  = *(const bf16x8*)(Qf + ra + 32);
    const float* up = Uv_in + off + w * 1024 + lane * 4;
    F.uv0 = *(const f32x4*)up;         F.uv1 = *(const f32x4*)(up + 256);
    F.uv2 = *(const f32x4*)(up + 512); F.uv3 = *(const f32x4*)(up + 768);
}

__device__ __forceinline__ void compute_chunk(const Frag& F, f32x4 (&Sacc)[4],
        bf16* __restrict__ obf, const float (&gmv)[4], int row0c, int col0, int w, int lane,
        bf16 (*ShT_h)[72], bf16 (*ShT_l)[72], bf16 (*Ut_h)[72], bf16 (*Ut_l)[72]) {
    const int fr = lane & 15, fg = lane >> 4;
    // m1: U = Uv - Uk*S0  (A = -Uk hi/lo, B = ShT hi/lo)
    f32x4 Uacc[4] = {F.uv0, F.uv1, F.uv2, F.uv3};
#pragma unroll
    for (int vt = 0; vt < 4; ++vt) {
        const bf16* sh0 = &ShT_h[vt * 16 + fr][fg * 8];
        const bf16* sl0 = &ShT_l[vt * 16 + fr][fg * 8];
        bf16x8 sh = *(const bf16x8*)sh0, sl = *(const bf16x8*)sl0;
        Uacc[vt] = MFMA(F.nkh0, sh, Uacc[vt]);
        Uacc[vt] = MFMA(F.nkh0, sl, Uacc[vt]);
        Uacc[vt] = MFMA(F.nkl0, sh, Uacc[vt]);
        sh = *(const bf16x8*)(sh0 + 32); sl = *(const bf16x8*)(sl0 + 32);
        Uacc[vt] = MFMA(F.nkh1, sh, Uacc[vt]);
        Uacc[vt] = MFMA(F.nkh1, sl, Uacc[vt]);
        Uacc[vt] = MFMA(F.nkl1, sh, Uacc[vt]);
    }
    // write U^T (split) to LDS
#pragma unroll
    for (int vt = 0; vt < 4; ++vt) {
        int vg = vt * 16 + fr;
#pragma unroll
        for (int j = 0; j < 4; ++j) {
            int tg = w * 16 + fg * 4 + j;
            float u = Uacc[vt][j];
            bf16 hh = (bf16)u;
            Ut_h[vg][tg] = hh;
            Ut_l[vg][tg] = (bf16)(u - (float)hh);
        }
    }
    __syncthreads();
    // m2: S += K^T U   |   O = Q*S0 + L*U
    f32x4 Oacc[4];
#pragma unroll
    for (int vt = 0; vt < 4; ++vt) Oacc[vt] = (f32x4){0, 0, 0, 0};
#pragma unroll
    for (int vt = 0; vt < 4; ++vt) {
        const bf16* uh0 = &Ut_h[vt * 16 + fr][fg * 8];
        const bf16* ul0 = &Ut_l[vt * 16 + fr][fg * 8];
        const bf16* so0 = &ShT_h[vt * 16 + fr][fg * 8];
        bf16x8 uh = *(const bf16x8*)uh0, ul = *(const bf16x8*)ul0, so = *(const bf16x8*)so0;
        Sacc[vt] = MFMA(F.kth0, uh, Sacc[vt]);
        Sacc[vt] = MFMA(F.kth0, ul, Sacc[vt]);
        Sacc[vt] = MFMA(F.ktl0, uh, Sacc[vt]);
        Oacc[vt] = MFMA(F.qf0, so, Oacc[vt]);
        Oacc[vt] = MFMA(F.lf0, uh, Oacc[vt]);
        uh = *(const bf16x8*)(uh0 + 32); ul = *(const bf16x8*)(ul0 + 32); so = *(const bf16x8*)(so0 + 32);
        Sacc[vt] = MFMA(F.kth1, uh, Sacc[vt]);
        Sacc[vt] = MFMA(F.kth1, ul, Sacc[vt]);
        Sacc[vt] = MFMA(F.ktl1, uh, Sacc[vt]);
        Oacc[vt] = MFMA(F.qf1, so, Oacc[vt]);
        Oacc[vt] = MFMA(F.lf1, uh, Oacc[vt]);
    }
    __syncthreads();   // all reads of old ShT done
    // fused per-head RMSNorm of Oacc rows -> obf ; write new ShT (split) from Sacc
    float ss0 = 0.f, ss1 = 0.f, ss2 = 0.f, ss3 = 0.f;
#pragma unroll
    for (int vt = 0; vt < 4; ++vt) {
        ss0 += Oacc[vt][0] * Oacc[vt][0];
        ss1 += Oacc[vt][1] * Oacc[vt][1];
        ss2 += Oacc[vt][2] * Oacc[vt][2];
        ss3 += Oacc[vt][3] * Oacc[vt][3];
    }
#pragma unroll
    for (int m = 1; m < 16; m <<= 1) {
        ss0 += __shfl_xor(ss0, m); ss1 += __shfl_xor(ss1, m);
        ss2 += __shfl_xor(ss2, m); ss3 += __shfl_xor(ss3, m);
    }
    float r0 = rsqrtf(ss0 * (1.f / 64.f) + 1e-6f);
    float r1 = rsqrtf(ss1 * (1.f / 64.f) + 1e-6f);
    float r2 = rsqrtf(ss2 * (1.f / 64.f) + 1e-6f);
    float r3 = rsqrtf(ss3 * (1.f / 64.f) + 1e-6f);
    const size_t orow = (size_t)(row0c + w * 16 + fg * 4) * DD + col0;
#pragma unroll
    for (int vt = 0; vt < 4; ++vt) {
        int vg = vt * 16 + fr;
#pragma unroll
        for (int j = 0; j < 4; ++j) {
            int tg = w * 16 + fg * 4 + j;
            float s = Sacc[vt][j];
            bf16 hh = (bf16)s;
            ShT_h[vg][tg] = hh;
            ShT_l[vg][tg] = (bf16)(s - (float)hh);
        }
        float g = gmv[vt];
        obf[orow + vg]          = (bf16)(Oacc[vt][0] * r0 * g);
        obf[orow + DD + vg]     = (bf16)(Oacc[vt][1] * r1 * g);
        obf[orow + 2 * DD + vg] = (bf16)(Oacc[vt][2] * r2 * g);
        obf[orow + 3 * DD + vg] = (bf16)(Oacc[vt][3] * r3 * g);
    }
    __syncthreads();
}

__global__ __launch_bounds__(256, 1) void k_scan2(
        const bf16* __restrict__ Qf, const bf16* __restrict__ L_in,
        const bf16* __restrict__ nUk_h, const bf16* __restrict__ nUk_l,
        const bf16* __restrict__ Kt_h, const bf16* __restrict__ Kt_l,
        const float* __restrict__ Uv_in, const float* __restrict__ gm,
        bf16* __restrict__ obf) {
    __shared__ bf16 ShT_h[64][72], ShT_l[64][72], Ut_h[64][72], Ut_l[64][72];
    const int tid = threadIdx.x, lane = tid & 63, w = tid >> 6;
    const int bh = blockIdx.x, b = bh >> 4, hh = bh & 15;
    const int col0 = hh * 64;
    for (int i = tid; i < 64 * 72; i += 256) {
        (&ShT_h[0][0])[i] = (bf16)0.f;
        (&ShT_l[0][0])[i] = (bf16)0.f;
    }
    __syncthreads();
    f32x4 Sacc[4];
#pragma unroll
    for (int vt = 0; vt < 4; ++vt) Sacc[vt] = (f32x4){0, 0, 0, 0};
    float gmv[4];
#pragma unroll
    for (int vt = 0; vt < 4; ++vt) gmv[vt] = gm[hh * 64 + vt * 16 + (lane & 15)];

    Frag fA, fB;
    auto offc = [&](int c) { return ((size_t)bh * 32 + c) * 4096; };
    load_frags(fA, nUk_h, nUk_l, Kt_h, Kt_l, L_in, Qf, Uv_in, offc(0), w, lane);
    for (int c = 0; c < 32; c += 2) {
        load_frags(fB, nUk_h, nUk_l, Kt_h, Kt_l, L_in, Qf, Uv_in, offc(c + 1), w, lane);
        compute_chunk(fA, Sacc, obf, gmv, b * TT + c * 64, col0, w, lane, ShT_h, ShT_l, Ut_h, Ut_l);
        if (c + 2 < 32)
            load_frags(fA, nUk_h, nUk_l, Kt_h, Kt_l, L_in, Qf, Uv_in, offc(c + 2), w, lane);
        compute_chunk(fB, Sacc, obf, gmv, b * TT + (c + 1) * 64, col0, w, lane, ShT_h, ShT_l, Ut_h, Ut_l);
    }
}

// ---------------- per-head RMSNorm * o_gamma, cast bf16 (row-major o, fallback path) ----------------
__global__ __launch_bounds__(256) void k_rms(const float* __restrict__ o, const float* __restrict__ gm,
                                             bf16* __restrict__ obf) {
    size_t row = (size_t)blockIdx.x * 4 + (threadIdx.x >> 6);
    int lane = threadIdx.x & 63;
    int h = (int)(row & 15);
    float x = o[row * 64 + lane];
    float ss = x * x;
#pragma unroll
    for (int m = 1; m < 64; m <<= 1) ss += __shfl_xor(ss, m);
    float y = x * rsqrtf(ss * (1.f / 64.f) + 1e-6f) * gm[h * 64 + lane];
    obf[row * 64 + lane] = (bf16)y;
}

// ---------------- residual + LayerNorm ----------------
__global__ __launch_bounds__(256) void k_ln(const float* __restrict__ yp, const float* __restrict__ x,
                                            const float* __restrict__ g, const float* __restrict__ bb,
                                            float* __restrict__ outp) {
    const int row = blockIdx.x;
    const int tid = threadIdx.x;
    __shared__ float red[8];
    const size_t base = (size_t)row * DD + tid * 4;
    float4 a  = *(const float4*)(yp + base);
    float4 b4 = *(const float4*)(x + base);
    float y0 = a.x + b4.x, y1 = a.y + b4.y, y2 = a.z + b4.z, y3 = a.w + b4.w;
    float s = (y0 + y1) + (y2 + y3);
#pragma unroll
    for (int m = 1; m < 64; m <<= 1) s += __shfl_xor(s, m);
    if ((tid & 63) == 0) red[tid >> 6] = s;
    __syncthreads();
    float mu = (red[0] + red[1] + red[2] + red[3]) * (1.f / (float)DD);
    float d0 = y0 - mu, d1 = y1 - mu, d2 = y2 - mu, d3 = y3 - mu;
    float sq = (d0 * d0 + d1 * d1) + (d2 * d2 + d3 * d3);
#pragma unroll
    for (int m = 1; m < 64; m <<= 1) sq += __shfl_xor(sq, m);
    if ((tid & 63) == 0) red[4 + (tid >> 6)] = sq;
    __syncthreads();
    float var = (red[4] + red[5] + red[6] + red[7]) * (1.f / (float)DD);
    float inv = rsqrtf(var + 1e-5f);
    const int c = tid * 4;
    float4 gg = *(const float4*)(g + c);
    float4 bv = *(const float4*)(bb + c);
    float4 r;
    r.x = d0 * inv * gg.x + bv.x;
    r.y = d1 * inv * gg.y + bv.y;
    r.z = d2 * inv * gg.z + bv.z;
    r.w = d3 * inv * gg.w + bv.w;
    *(float4*)(outp + base) = r;
}

// ---------------- launcher ----------------
extern "C" void kernel_launch(void* const* d_in, const int* in_sizes, int n_in,
                              void* d_out, int out_size, void* d_ws, size_t ws_size,
                              hipStream_t stream) {
    (void)in_sizes; (void)n_in; (void)out_size;
    if (ws_size < ((size_t)81 << 20)) return;
    const bool fast = ws_size >= ((size_t)137 << 20);

    const float* x   = (const float*)d_in[0];
    const float* Wq  = (const float*)d_in[1];
    const float* Wk  = (const float*)d_in[2];
    const float* Wv  = (const float*)d_in[3];
    const float* Wb  = (const float*)d_in[4];
    const float* gma = (const float*)d_in[5];
    const float* Wo  = (const float*)d_in[6];
    const float* lng = (const float*)d_in[7];
    const float* lnb = (const float*)d_in[8];
    float* outp = (float*)d_out;

    char* ws = (char*)d_ws;
    bf16*  xb    = (bf16*)(ws);                         // 8 MiB
    bf16*  WqT   = (bf16*)(ws + ((size_t)8  << 20));    // 2 MiB each
    bf16*  WoT   = (bf16*)(ws + ((size_t)14 << 20));
    float* q     = (float*)(ws + ((size_t)16 << 20));
    float* k     = (float*)(ws + ((size_t)32 << 20));
    float* v     = (float*)(ws + ((size_t)48 << 20));
    float* beta  = (float*)(ws + ((size_t)64 << 20));
    bf16*  wf    = (bf16*)(ws + ((size_t)64 << 20) + (1 << 19));  // 32 KiB frag-ordered Wb
    float* o     = (float*)(ws + ((size_t)65 << 20));   // fallback-path o (16 MiB)
    bf16*  Qfrag = (bf16*)(ws + ((size_t)65 << 20));    // fast-path Q fragments (8 MiB, reuses o slot)
    bf16*  obf   = (bf16*)(ws);                         // reuse xb
    float* yproj = (float*)(ws + ((size_t)16 << 20));   // reuse q (dead after prep: Qfrag holds Q)
    // chunked-scan scratch (fast path)
    bf16*  Lbf   = (bf16*)(ws + ((size_t)81  << 20));   // 8 MiB
    bf16*  nUk_h = (bf16*)(ws + ((size_t)89  << 20));
    bf16*  nUk_l = (bf16*)(ws + ((size_t)97  << 20));
    bf16*  Kt_h  = (bf16*)(ws + ((size_t)105 << 20));
    bf16*  Kt_l  = (bf16*)(ws + ((size_t)113 << 20));
    float* Uv    = (float*)(ws + ((size_t)121 << 20));  // 16 MiB

    bf16* WkT = WqT + (size_t)DD * DD;
    bf16* WvT = WkT + (size_t)DD * DD;

    k_wbfrag<<<8, 256, 0, stream>>>(Wb, wf);
    k_cvt<<<2048, 256, 0, stream>>>(x, xb);
    k_transpose_cvt4<<<dim3(16, 16, 4), 256, 0, stream>>>(Wq, Wk, Wv, Wo, WqT, WkT, WvT, WoT);
    k_gemm_qkv<<<dim3(32, 8, 3), 256, 0, stream>>>(xb, WqT, q);
    k_beta2<<<256, 64, 0, stream>>>(xb, wf, beta);
    k_actnorm<<<32768, 256, 0, stream>>>(q);   // q,k contiguous: one launch covers both
    if (fast) {
        k_prep<<<dim3(32, 32), 256, 0, stream>>>(q, k, v, beta, Lbf, nUk_h, nUk_l, Kt_h, Kt_l, Uv, Qfrag);
        k_scan2<<<32, 256, 0, stream>>>(Qfrag, Lbf, nUk_h, nUk_l, Kt_h, Kt_l, Uv, gma, obf);
    } else {
        k_scan<<<32, 256, 0, stream>>>(q, k, v, beta, o);
        k_rms<<<16384, 256, 0, stream>>>(o, gma, obf);
    }
    k_gemm<<<dim3(32, 8), 256, 0, stream>>>(obf, WoT, yproj);
    k_ln<<<4096, 256, 0, stream>>>(yproj, x, lng, lnb, outp);
}

// Round 12
// 310.466 us; speedup vs baseline: 1.1173x; 1.0530x over previous
//
#include <hip/hip_runtime.h>
#include <hip/hip_bf16.h>
#include <cstdint>

#define BB 2
#define TT 2048
#define DD 1024
#define HH 16
#define DH 64
#define MM (BB*TT)      // 4096 rows
constexpr int KDIM = 1024;
constexpr int NDIM = 1024;

typedef __bf16 bf16;
typedef __attribute__((ext_vector_type(8))) __bf16 bf16x8;
typedef __attribute__((ext_vector_type(4))) float f32x4;

#define MFMA(a,b,c) __builtin_amdgcn_mfma_f32_16x16x32_bf16((a),(b),(c),0,0,0)

// async global->LDS, 16B per lane (HW: dest = wave-uniform base + lane*16)
__device__ __forceinline__ void gload16(const bf16* g, bf16* l) {
    __builtin_amdgcn_global_load_lds(
        (const __attribute__((address_space(1))) unsigned int*)g,
        (__attribute__((address_space(3))) unsigned int*)l, 16, 0, 0);
}

// ---------------- elementwise: f32 -> bf16 cast (x -> xb) ----------------
__global__ __launch_bounds__(256) void k_cvt(const float* __restrict__ in, bf16* __restrict__ outp) {
    size_t i = ((size_t)blockIdx.x * 256 + threadIdx.x) * 8;
    float4 a = *(const float4*)(in + i);
    float4 b = *(const float4*)(in + i + 4);
    bf16x8 r;
    r[0] = (bf16)a.x; r[1] = (bf16)a.y; r[2] = (bf16)a.z; r[3] = (bf16)a.w;
    r[4] = (bf16)b.x; r[5] = (bf16)b.y; r[6] = (bf16)b.z; r[7] = (bf16)b.w;
    *(bf16x8*)(outp + i) = r;
}

// ---------------- transpose + cast x4: W (K x N) f32 -> W^T (N x K) bf16, z picks tensor ----
__global__ __launch_bounds__(256) void k_transpose_cvt4(
        const float* __restrict__ i0, const float* __restrict__ i1,
        const float* __restrict__ i2, const float* __restrict__ i3,
        bf16* __restrict__ o0, bf16* __restrict__ o1,
        bf16* __restrict__ o2, bf16* __restrict__ o3) {
    __shared__ float tile[64][65];
    const float* in; bf16* outp;
    switch (blockIdx.z) {
        case 0:  in = i0; outp = o0; break;
        case 1:  in = i1; outp = o1; break;
        case 2:  in = i2; outp = o2; break;
        default: in = i3; outp = o3; break;
    }
    const int tx = threadIdx.x & 63;
    const int ty = threadIdx.x >> 6;
    const int r0 = blockIdx.y * 64, c0 = blockIdx.x * 64;
#pragma unroll
    for (int i = 0; i < 16; ++i) {
        int rr = ty * 16 + i;
        tile[rr][tx] = in[(size_t)(r0 + rr) * 1024 + c0 + tx];
    }
    __syncthreads();
#pragma unroll
    for (int i = 0; i < 16; ++i) {
        int rr = ty * 16 + i;
        outp[(size_t)(c0 + rr) * 1024 + r0 + tx] = (bf16)tile[tx][rr];
    }
}

// ---------------- GEMM: A (M x K, bf16 rm) @ Bt (N x K, bf16 rm) -> C f32 (bf16-rounded) ----
// global_load_lds staging: linear LDS dest, pre-swizzled global source (rule #21 both-sides).
// Layout invariant: logical k-chunk c of row r lives at physical chunk c ^ (r&7).
#define BM 128
#define BN 128
#define BKT 64

__device__ __forceinline__ void gemm_core(const bf16* __restrict__ A, const bf16* __restrict__ Bt,
                                          float* __restrict__ Cc) {
    __shared__ __align__(16) bf16 As[BM * BKT];
    __shared__ __align__(16) bf16 Bs[BN * BKT];
    const int tid  = threadIdx.x;
    const int lane = tid & 63;
    const int w    = tid >> 6;
    const int wr   = w >> 1, wc = w & 1;
    const int bm   = blockIdx.x * BM;
    const int bn   = blockIdx.y * BN;

    f32x4 acc[4][4];
#pragma unroll
    for (int m_ = 0; m_ < 4; ++m_)
#pragma unroll
        for (int n = 0; n < 4; ++n) acc[m_][n] = (f32x4){0.f, 0.f, 0.f, 0.f};

    const int fr = lane & 15;
    const int fg = lane >> 4;
    // gl_lds: lane covers row w*8 + (lane>>3) of each 32-row slab; physical chunk lane&7.
    // Source pre-swizzle: load logical chunk (lane&7)^((lane>>3)&7) so landed layout = c^(r&7).
    const int lrow = w * 8 + (lane >> 3);
    const int swz  = (lane & 7) ^ ((lane >> 3) & 7);
    const bf16* Ap = A  + (size_t)(bm + lrow) * KDIM + swz * 8;
    const bf16* Bp = Bt + (size_t)(bn + lrow) * KDIM + swz * 8;
    bf16* Asw = As + w * 8 * BKT;    // wave-uniform LDS base (+ i*32 rows per slab)
    bf16* Bsw = Bs + w * 8 * BKT;

    for (int kt = 0; kt < KDIM; kt += BKT) {
        if (kt) __syncthreads();     // previous tile's LDS reads complete
#pragma unroll
        for (int i = 0; i < 4; ++i) {
            gload16(Ap + (size_t)i * 32 * KDIM + kt, Asw + i * 32 * BKT);
            gload16(Bp + (size_t)i * 32 * KDIM + kt, Bsw + i * 32 * BKT);
        }
        __syncthreads();             // barrier drains vmcnt -> loads landed
#pragma unroll
        for (int s = 0; s < 2; ++s) {
            bf16x8 af[4], bfv[4];
#pragma unroll
            for (int m_ = 0; m_ < 4; ++m_) {
                int row = wr * 64 + m_ * 16 + fr;
                int p   = (s * 4 + fg) ^ (row & 7);
                af[m_] = *(const bf16x8*)(As + row * BKT + p * 8);
            }
#pragma unroll
            for (int n = 0; n < 4; ++n) {
                int row = wc * 64 + n * 16 + fr;
                int p   = (s * 4 + fg) ^ (row & 7);
                bfv[n] = *(const bf16x8*)(Bs + row * BKT + p * 8);
            }
#pragma unroll
            for (int m_ = 0; m_ < 4; ++m_)
#pragma unroll
                for (int n = 0; n < 4; ++n)
                    acc[m_][n] = MFMA(af[m_], bfv[n], acc[m_][n]);
        }
    }
#pragma unroll
    for (int m_ = 0; m_ < 4; ++m_) {
        int row0 = bm + wr * 64 + m_ * 16 + fg * 4;
#pragma unroll
        for (int j = 0; j < 4; ++j)
#pragma unroll
            for (int n = 0; n < 4; ++n) {
                int col = bn + wc * 64 + n * 16 + fr;
                Cc[(size_t)(row0 + j) * NDIM + col] = (float)((bf16)acc[m_][n][j]);
            }
    }
}

__global__ __launch_bounds__(256) void k_gemm(const bf16* __restrict__ A, const bf16* __restrict__ Bt,
                                              float* __restrict__ Cc) {
    gemm_core(A, Bt, Cc);
}

__global__ __launch_bounds__(256) void k_gemm_qkv(const bf16* __restrict__ A, const bf16* __restrict__ WtBase,
                                                  float* __restrict__ outBase) {
    int z = blockIdx.z;
    gemm_core(A, WtBase + (size_t)z * (DD * DD), outBase + (size_t)z * ((size_t)MM * DD));
}

// ---------------- Wb (1024x16 f32) -> fragment-ordered bf16 [s][lane][e] ----------------
__global__ __launch_bounds__(256) void k_wbfrag(const float* __restrict__ Wb, bf16* __restrict__ wf) {
    int i = blockIdx.x * 256 + threadIdx.x;   // 2048 slots (32 s-steps x 64 lanes)
    int s = i >> 6, l = i & 63;
    int h = l & 15, kb = (l >> 4) * 8;
    bf16x8 r;
#pragma unroll
    for (int e = 0; e < 8; ++e) r[e] = (bf16)Wb[(size_t)(s * 32 + kb + e) * HH + h];
    *(bf16x8*)(wf + (size_t)i * 8) = r;
}

// ---------------- beta = 2*sigmoid(bf16round(xb @ Wb_bf16)) via MFMA ----------------
__global__ __launch_bounds__(64) void k_beta2(const bf16* __restrict__ xb, const bf16* __restrict__ wf,
                                              float* __restrict__ beta) {
    const int lane = threadIdx.x;
    const int fr = lane & 15, fg = lane >> 4;
    const int tile = blockIdx.x;
    const bf16* ap = xb + (size_t)(tile * 16 + fr) * DD + fg * 8;
    f32x4 acc = (f32x4){0.f, 0.f, 0.f, 0.f};
#pragma unroll
    for (int s = 0; s < 32; ++s) {
        bf16x8 a = *(const bf16x8*)(ap + s * 32);
        bf16x8 b = *(const bf16x8*)(wf + ((size_t)s * 64 + lane) * 8);
        acc = MFMA(a, b, acc);
    }
#pragma unroll
    for (int j = 0; j < 4; ++j) {
        float rr = (float)((bf16)acc[j]);       // jnp bf16 matmul rounds before astype(f32)
        beta[(size_t)(tile * 16 + fg * 4 + j) * HH + fr] = 2.f / (1.f + expf(-rr));
    }
}

// ---------------- silu + per-head l2norm, in place (q and k contiguous: one launch) ----------------
__global__ __launch_bounds__(256) void k_actnorm(float* __restrict__ a) {
    size_t row = (size_t)blockIdx.x * 4 + (threadIdx.x >> 6);
    int lane = threadIdx.x & 63;
    float x = a[row * 64 + lane];
    float e = x / (1.f + expf(-x));
    float ss = e * e;
#pragma unroll
    for (int m = 1; m < 64; m <<= 1) ss += __shfl_xor(ss, m);
    a[row * 64 + lane] = e * rsqrtf(ss + 1e-6f);
}

// ---------------- OLD sequential delta-rule scan (fallback if ws too small) ----------------
__global__ __launch_bounds__(256) void k_scan(const float* __restrict__ Qv, const float* __restrict__ Kv,
                                              const float* __restrict__ Vv, const float* __restrict__ Bv,
                                              float* __restrict__ Ov) {
    const int bh = blockIdx.x;
    const int b = bh >> 4, h = bh & 15;
    const int tid = threadIdx.x;
    const int r   = tid >> 2;
    const int seg = tid & 3;
    float S[16];
#pragma unroll
    for (int j = 0; j < 16; ++j) S[j] = 0.f;
    const size_t base = ((size_t)b * TT) * DD + (size_t)h * DH;
    const float* kp = Kv + base + seg * 16;
    const float* qp = Qv + base + seg * 16;
    const float* vp = Vv + base + r;
    const float* bp = Bv + ((size_t)b * TT) * HH + h;
    float* op = Ov + base + r;

    float4 k0, k1, k2, k3, q0, q1, q2, q3;
    float vv, bt;
    k0 = *(const float4*)(kp + 0);  k1 = *(const float4*)(kp + 4);
    k2 = *(const float4*)(kp + 8);  k3 = *(const float4*)(kp + 12);
    q0 = *(const float4*)(qp + 0);  q1 = *(const float4*)(qp + 4);
    q2 = *(const float4*)(qp + 8);  q3 = *(const float4*)(qp + 12);
    vv = *vp; bt = *bp;

    for (int t = 0; t < TT; ++t) {
        float4 nk0, nk1, nk2, nk3, nq0, nq1, nq2, nq3;
        float nvv = 0.f, nbt = 0.f;
        if (t + 1 < TT) {
            const float* kn = kp + (size_t)(t + 1) * DD;
            const float* qn = qp + (size_t)(t + 1) * DD;
            nk0 = *(const float4*)(kn + 0);  nk1 = *(const float4*)(kn + 4);
            nk2 = *(const float4*)(kn + 8);  nk3 = *(const float4*)(kn + 12);
            nq0 = *(const float4*)(qn + 0);  nq1 = *(const float4*)(qn + 4);
            nq2 = *(const float4*)(qn + 8);  nq3 = *(const float4*)(qn + 12);
            nvv = vp[(size_t)(t + 1) * DD];
            nbt = bp[(size_t)(t + 1) * HH];
        }
        float a0, a1, a2, a3;
        a0 = S[0] * k0.x;  a1 = S[1] * k0.y;  a2 = S[2] * k0.z;  a3 = S[3] * k0.w;
        a0 = fmaf(S[4],  k1.x, a0); a1 = fmaf(S[5],  k1.y, a1); a2 = fmaf(S[6],  k1.z, a2); a3 = fmaf(S[7],  k1.w, a3);
        a0 = fmaf(S[8],  k2.x, a0); a1 = fmaf(S[9],  k2.y, a1); a2 = fmaf(S[10], k2.z, a2); a3 = fmaf(S[11], k2.w, a3);
        a0 = fmaf(S[12], k3.x, a0); a1 = fmaf(S[13], k3.y, a1); a2 = fmaf(S[14], k3.z, a2); a3 = fmaf(S[15], k3.w, a3);
        float sk = (a0 + a1) + (a2 + a3);
        sk += __shfl_xor(sk, 1); sk += __shfl_xor(sk, 2);
        const float wgt = bt * (vv - sk);
        float o0, o1, o2, o3;
        S[0]  = fmaf(wgt, k0.x, S[0]);  o0 = S[0] * q0.x;
        S[1]  = fmaf(wgt, k0.y, S[1]);  o1 = S[1] * q0.y;
        S[2]  = fmaf(wgt, k0.z, S[2]);  o2 = S[2] * q0.z;
        S[3]  = fmaf(wgt, k0.w, S[3]);  o3 = S[3] * q0.w;
        S[4]  = fmaf(wgt, k1.x, S[4]);  o0 = fmaf(S[4],  q1.x, o0);
        S[5]  = fmaf(wgt, k1.y, S[5]);  o1 = fmaf(S[5],  q1.y, o1);
        S[6]  = fmaf(wgt, k1.z, S[6]);  o2 = fmaf(S[6],  q1.z, o2);
        S[7]  = fmaf(wgt, k1.w, S[7]);  o3 = fmaf(S[7],  q1.w, o3);
        S[8]  = fmaf(wgt, k2.x, S[8]);  o0 = fmaf(S[8],  q2.x, o0);
        S[9]  = fmaf(wgt, k2.y, S[9]);  o1 = fmaf(S[9],  q2.y, o1);
        S[10] = fmaf(wgt, k2.z, S[10]); o2 = fmaf(S[10], q2.z, o2);
        S[11] = fmaf(wgt, k2.w, S[11]); o3 = fmaf(S[11], q2.w, o3);
        S[12] = fmaf(wgt, k3.x, S[12]); o0 = fmaf(S[12], q3.x, o0);
        S[13] = fmaf(wgt, k3.y, S[13]); o1 = fmaf(S[13], q3.y, o1);
        S[14] = fmaf(wgt, k3.z, S[14]); o2 = fmaf(S[14], q3.z, o2);
        S[15] = fmaf(wgt, k3.w, S[15]); o3 = fmaf(S[15], q3.w, o3);
        float oo = (o0 + o1) + (o2 + o3);
        oo += __shfl_xor(oo, 1); oo += __shfl_xor(oo, 2);
        if (seg == 0) op[(size_t)t * DD] = oo;
        k0 = nk0; k1 = nk1; k2 = nk2; k3 = nk3;
        q0 = nq0; q1 = nq1; q2 = nq2; q3 = nq3;
        vv = nvv; bt = nbt;
    }
}

// =================== CHUNKED WY SCAN ===================
// Chunk C=64. k_prep (parallel): A = tril(beta*K.K^T), solve (I+A)[Uv|Uk] = diag(beta)[V|K],
// L = tril(Q.K^T), Qf = bf16 Q fragments. k_scan2 (sequential, 4 waves, S/O interleaved,
// latency-bound at 1 block/CU -> keep critical chain short):
//   U  = Uv - Uk * S0          (bf16x2 MFMA, acc init = Uv fp32)
//   O  = Q*S0 + L*U -> fused per-head RMSNorm -> obf  (plain bf16 MFMA)
//   S1 = S0 + K^T * U          (bf16x2 MFMA)

__device__ __forceinline__ int uv_idx(int t, int vv) {
    // fragment-order so phase2 wave w loads f32x4 at ((w*4+vt)*64 + lane)*4
    return (((t >> 4) * 4 + (vv >> 4)) * 64 + (((t >> 2) & 3) * 16 + (vv & 15))) * 4 + (t & 3);
}

__global__ __launch_bounds__(256, 3) void k_prep(
        const float* __restrict__ q, const float* __restrict__ k, const float* __restrict__ v,
        const float* __restrict__ beta,
        bf16* __restrict__ L_out, bf16* __restrict__ nUk_h, bf16* __restrict__ nUk_l,
        bf16* __restrict__ Kt_h, bf16* __restrict__ Kt_l, float* __restrict__ Uv_out,
        bf16* __restrict__ Qf) {
    __shared__ float Ash[64][65];
    __shared__ bf16 Khi[64][72], Klo[64][72];
    __shared__ float bsh[64];

    const int tid = threadIdx.x;
    const int c = blockIdx.x, bh = blockIdx.y, b = bh >> 4, h = bh & 15;
    const int row0 = b * TT + c * 64, col0 = h * 64;
    const size_t off = ((size_t)bh * 32 + c) * 4096;
    const int lane = tid & 63, w = tid >> 6;
    const int fr = lane & 15, fg = lane >> 4;

    // ---- early global loads ----
    const int cslice = (w & 1) * 32;
    const float* rp = ((w >= 2) ? k : v) + (size_t)(row0 + lane) * DD + col0 + cslice;
    float4 rv[8];
#pragma unroll
    for (int a = 0; a < 8; ++a) rv[a] = *(const float4*)(rp + a * 4);
    const float* qfp = q + (size_t)(row0 + w * 16 + fr) * DD + col0 + fg * 8;
    float4 qa = *(const float4*)qfp, qb = *(const float4*)(qfp + 4);
    float4 qc = *(const float4*)(qfp + 32), qd = *(const float4*)(qfp + 36);
    const int tr = tid >> 2, cs = (tid & 3) * 16;
    float4 kv[4];
    const size_t rb = (size_t)(row0 + tr) * DD + col0 + cs;
#pragma unroll
    for (int j = 0; j < 4; ++j) kv[j] = *(const float4*)(k + rb + j * 4);

    if (tid < 64) bsh[tid] = beta[(size_t)(row0 + tid) * HH + h];
#pragma unroll
    for (int j = 0; j < 4; ++j) {
        int cb = cs + j * 4;
        float a0 = kv[j].x, a1 = kv[j].y, a2 = kv[j].z, a3 = kv[j].w;
        bf16 h0 = (bf16)a0, h1 = (bf16)a1, h2 = (bf16)a2, h3 = (bf16)a3;
        Khi[tr][cb] = h0; Khi[tr][cb+1] = h1; Khi[tr][cb+2] = h2; Khi[tr][cb+3] = h3;
        Klo[tr][cb]   = (bf16)(a0 - (float)h0);
        Klo[tr][cb+1] = (bf16)(a1 - (float)h1);
        Klo[tr][cb+2] = (bf16)(a2 - (float)h2);
        Klo[tr][cb+3] = (bf16)(a3 - (float)h3);
    }
    __syncthreads();

    // ---- MFMA: A_raw = K.K^T (bf16x2), L = tril(Q.K^T); store Qf fragments ----
    {
        bf16x8 aqh0, aqh1;
        aqh0[0]=(bf16)qa.x; aqh0[1]=(bf16)qa.y; aqh0[2]=(bf16)qa.z; aqh0[3]=(bf16)qa.w;
        aqh0[4]=(bf16)qb.x; aqh0[5]=(bf16)qb.y; aqh0[6]=(bf16)qb.z; aqh0[7]=(bf16)qb.w;
        aqh1[0]=(bf16)qc.x; aqh1[1]=(bf16)qc.y; aqh1[2]=(bf16)qc.z; aqh1[3]=(bf16)qc.w;
        aqh1[4]=(bf16)qd.x; aqh1[5]=(bf16)qd.y; aqh1[6]=(bf16)qd.z; aqh1[7]=(bf16)qd.w;
        {   // Qf fragment store (same values scan2 previously built in-loop)
            const size_t ra = off + (size_t)(w * 16 + fr) * 64 + fg * 8;
            *(bf16x8*)(Qf + ra) = aqh0;
            *(bf16x8*)(Qf + ra + 32) = aqh1;
        }
        f32x4 accA[4], accL[4];
#pragma unroll
        for (int it = 0; it < 4; ++it) { accA[it] = (f32x4){0,0,0,0}; accL[it] = (f32x4){0,0,0,0}; }
        bf16x8 akh0 = *(const bf16x8*)&Khi[w*16+fr][fg*8];
        bf16x8 akh1 = *(const bf16x8*)&Khi[w*16+fr][fg*8+32];
        bf16x8 akl0 = *(const bf16x8*)&Klo[w*16+fr][fg*8];
        bf16x8 akl1 = *(const bf16x8*)&Klo[w*16+fr][fg*8+32];
#pragma unroll
        for (int it = 0; it < 4; ++it) {
            bf16x8 bh0 = *(const bf16x8*)&Khi[it*16+fr][fg*8];
            bf16x8 bl0 = *(const bf16x8*)&Klo[it*16+fr][fg*8];
            accA[it] = MFMA(akh0, bh0, accA[it]);
            accA[it] = MFMA(akh0, bl0, accA[it]);
            accA[it] = MFMA(akl0, bh0, accA[it]);
            accL[it] = MFMA(aqh0, bh0, accL[it]);
            bf16x8 bh1 = *(const bf16x8*)&Khi[it*16+fr][fg*8+32];
            bf16x8 bl1 = *(const bf16x8*)&Klo[it*16+fr][fg*8+32];
            accA[it] = MFMA(akh1, bh1, accA[it]);
            accA[it] = MFMA(akh1, bl1, accA[it]);
            accA[it] = MFMA(akl1, bh1, accA[it]);
            accL[it] = MFMA(aqh1, bh1, accL[it]);
        }
#pragma unroll
        for (int it = 0; it < 4; ++it)
#pragma unroll
            for (int j = 0; j < 4; ++j) {
                int tg = w * 16 + fg * 4 + j, ig = it * 16 + fr;
                Ash[tg][ig] = (ig < tg) ? bsh[tg] * accA[it][j] : 0.f;
                L_out[off + tg * 64 + ig] = (ig <= tg) ? (bf16)accL[it][j] : (bf16)0.f;
            }
    }
    __syncthreads();

    // ---- barrier-free substitution: X[t][col] in registers, lane=row ----
    float bt = bsh[lane];
    float X[32];
#pragma unroll
    for (int a = 0; a < 8; ++a) {
        X[a*4+0] = bt * rv[a].x; X[a*4+1] = bt * rv[a].y;
        X[a*4+2] = bt * rv[a].z; X[a*4+3] = bt * rv[a].w;
    }
#pragma unroll 1
    for (int i = 0; i < 63; ++i) {
        float a = Ash[lane][i];          // conflict-free: stride-65, 2 lanes/bank
#pragma unroll
        for (int j = 0; j < 32; ++j) {
            float s = __uint_as_float(__builtin_amdgcn_readlane(__float_as_uint(X[j]), i));
            X[j] = fmaf(-a, s, X[j]);    // a==0 for i>=lane (zero-padded A)
        }
    }

    // ---- outputs ----
    if (w < 2) {                         // V columns -> Uv (fp32, fragment order)
#pragma unroll
        for (int j = 0; j < 32; ++j)
            Uv_out[off + uv_idx(lane, cslice + j)] = X[j];
    } else {                             // K columns -> -Uk hi/lo
#pragma unroll
        for (int g = 0; g < 4; ++g) {
            bf16x8 hi8, lo8;
#pragma unroll
            for (int e = 0; e < 8; ++e) {
                float nk = -X[g*8+e];
                bf16 nh = (bf16)nk;
                hi8[e] = nh;
                lo8[e] = (bf16)(nk - (float)nh);
            }
            *(bf16x8*)(nUk_h + off + (size_t)lane*64 + cslice + g*8) = hi8;
            *(bf16x8*)(nUk_l + off + (size_t)lane*64 + cslice + g*8) = lo8;
        }
    }
#pragma unroll
    for (int j = 0; j < 16; ++j) {
        int vc = cs + j;
        Kt_h[off + (size_t)tr*64 + vc] = Khi[vc][tr];
        Kt_l[off + (size_t)tr*64 + vc] = Klo[vc][tr];
    }
}

struct Frag {
    bf16x8 nkh0, nkh1, nkl0, nkl1;
    bf16x8 kth0, kth1, ktl0, ktl1;
    bf16x8 lf0, lf1, qf0, qf1;
    f32x4 uv0, uv1, uv2, uv3;
};

__device__ __forceinline__ void load_frags(Frag& F,
        const bf16* __restrict__ nUk_h, const bf16* __restrict__ nUk_l,
        const bf16* __restrict__ Kt_h, const bf16* __restrict__ Kt_l,
        const bf16* __restrict__ L_in, const bf16* __restrict__ Qf,
        const float* __restrict__ Uv_in, size_t off, int w, int lane) {
    const int fr = lane & 15, fg = lane >> 4;
    const size_t ra = off + (size_t)(w * 16 + fr) * 64 + fg * 8;
    F.nkh0 = *(const bf16x8*)(nUk_h + ra); F.nkh1 = *(const bf16x8*)(nUk_h + ra + 32);
    F.nkl0 = *(const bf16x8*)(nUk_l + ra); F.nkl1 = *(const bf16x8*)(nUk_l + ra + 32);
    F.kth0 = *(const bf16x8*)(Kt_h + ra);  F.kth1 = *(const bf16x8*)(Kt_h + ra + 32);
    F.ktl0 = *(const bf16x8*)(Kt_l + ra);  F.ktl1 = *(const bf16x8*)(Kt_l + ra + 32);
    F.lf0  = *(const bf16x8*)(L_in + ra);  F.lf1  = *(const bf16x8*)(L_in + ra + 32);
    F.qf0  = *(const bf16x8*)(Qf + ra);    F.qf1  = *(const bf16x8*)(Qf + ra + 32);
    const float* up = Uv_in + off + w * 1024 + lane * 4;
    F.uv0 = *(const f32x4*)up;         F.uv1 = *(const f32x4*)(up + 256);
    F.uv2 = *(const f32x4*)(up + 512); F.uv3 = *(const f32x4*)(up + 768);
}

__device__ __forceinline__ void compute_chunk(const Frag& F, f32x4 (&Sacc)[4],
        bf16* __restrict__ obf, const float (&gmv)[4], int row0c, int col0, int w, int lane,
        bf16 (*ShT_h)[72], bf16 (*ShT_l)[72], bf16 (*Ut_h)[72], bf16 (*Ut_l)[72]) {
    const int fr = lane & 15, fg = lane >> 4;
    // m1: U = Uv - Uk*S0  (A = -Uk hi/lo, B = ShT hi/lo)
    f32x4 Uacc[4] = {F.uv0, F.uv1, F.uv2, F.uv3};
#pragma unroll
    for (int vt = 0; vt < 4; ++vt) {
        const bf16* sh0 = &ShT_h[vt * 16 + fr][fg * 8];
        const bf16* sl0 = &ShT_l[vt * 16 + fr][fg * 8];
        bf16x8 sh = *(const bf16x8*)sh0, sl = *(const bf16x8*)sl0;
        Uacc[vt] = MFMA(F.nkh0, sh, Uacc[vt]);
        Uacc[vt] = MFMA(F.nkh0, sl, Uacc[vt]);
        Uacc[vt] = MFMA(F.nkl0, sh, Uacc[vt]);
        sh = *(const bf16x8*)(sh0 + 32); sl = *(const bf16x8*)(sl0 + 32);
        Uacc[vt] = MFMA(F.nkh1, sh, Uacc[vt]);
        Uacc[vt] = MFMA(F.nkh1, sl, Uacc[vt]);
        Uacc[vt] = MFMA(F.nkl1, sh, Uacc[vt]);
    }
    // write U^T (split) to LDS
#pragma unroll
    for (int vt = 0; vt < 4; ++vt) {
        int vg = vt * 16 + fr;
#pragma unroll
        for (int j = 0; j < 4; ++j) {
            int tg = w * 16 + fg * 4 + j;
            float u = Uacc[vt][j];
            bf16 hh = (bf16)u;
            Ut_h[vg][tg] = hh;
            Ut_l[vg][tg] = (bf16)(u - (float)hh);
        }
    }
    __syncthreads();
    // m2: S += K^T U   |   O = Q*S0 + L*U
    f32x4 Oacc[4];
#pragma unroll
    for (int vt = 0; vt < 4; ++vt) Oacc[vt] = (f32x4){0, 0, 0, 0};
#pragma unroll
    for (int vt = 0; vt < 4; ++vt) {
        const bf16* uh0 = &Ut_h[vt * 16 + fr][fg * 8];
        const bf16* ul0 = &Ut_l[vt * 16 + fr][fg * 8];
        const bf16* so0 = &ShT_h[vt * 16 + fr][fg * 8];
        bf16x8 uh = *(const bf16x8*)uh0, ul = *(const bf16x8*)ul0, so = *(const bf16x8*)so0;
        Sacc[vt] = MFMA(F.kth0, uh, Sacc[vt]);
        Sacc[vt] = MFMA(F.kth0, ul, Sacc[vt]);
        Sacc[vt] = MFMA(F.ktl0, uh, Sacc[vt]);
        Oacc[vt] = MFMA(F.qf0, so, Oacc[vt]);
        Oacc[vt] = MFMA(F.lf0, uh, Oacc[vt]);
        uh = *(const bf16x8*)(uh0 + 32); ul = *(const bf16x8*)(ul0 + 32); so = *(const bf16x8*)(so0 + 32);
        Sacc[vt] = MFMA(F.kth1, uh, Sacc[vt]);
        Sacc[vt] = MFMA(F.kth1, ul, Sacc[vt]);
        Sacc[vt] = MFMA(F.ktl1, uh, Sacc[vt]);
        Oacc[vt] = MFMA(F.qf1, so, Oacc[vt]);
        Oacc[vt] = MFMA(F.lf1, uh, Oacc[vt]);
    }
    __syncthreads();   // all reads of old ShT done
    // fused per-head RMSNorm of Oacc rows -> obf ; write new ShT (split) from Sacc
    float ss0 = 0.f, ss1 = 0.f, ss2 = 0.f, ss3 = 0.f;
#pragma unroll
    for (int vt = 0; vt < 4; ++vt) {
        ss0 += Oacc[vt][0] * Oacc[vt][0];
        ss1 += Oacc[vt][1] * Oacc[vt][1];
        ss2 += Oacc[vt][2] * Oacc[vt][2];
        ss3 += Oacc[vt][3] * Oacc[vt][3];
    }
#pragma unroll
    for (int m = 1; m < 16; m <<= 1) {
        ss0 += __shfl_xor(ss0, m); ss1 += __shfl_xor(ss1, m);
        ss2 += __shfl_xor(ss2, m); ss3 += __shfl_xor(ss3, m);
    }
    float r0 = rsqrtf(ss0 * (1.f / 64.f) + 1e-6f);
    float r1 = rsqrtf(ss1 * (1.f / 64.f) + 1e-6f);
    float r2 = rsqrtf(ss2 * (1.f / 64.f) + 1e-6f);
    float r3 = rsqrtf(ss3 * (1.f / 64.f) + 1e-6f);
    const size_t orow = (size_t)(row0c + w * 16 + fg * 4) * DD + col0;
#pragma unroll
    for (int vt = 0; vt < 4; ++vt) {
        int vg = vt * 16 + fr;
#pragma unroll
        for (int j = 0; j < 4; ++j) {
            int tg = w * 16 + fg * 4 + j;
            float s = Sacc[vt][j];
            bf16 hh = (bf16)s;
            ShT_h[vg][tg] = hh;
            ShT_l[vg][tg] = (bf16)(s - (float)hh);
        }
        float g = gmv[vt];
        obf[orow + vg]          = (bf16)(Oacc[vt][0] * r0 * g);
        obf[orow + DD + vg]     = (bf16)(Oacc[vt][1] * r1 * g);
        obf[orow + 2 * DD + vg] = (bf16)(Oacc[vt][2] * r2 * g);
        obf[orow + 3 * DD + vg] = (bf16)(Oacc[vt][3] * r3 * g);
    }
    __syncthreads();
}

__global__ __launch_bounds__(256, 1) void k_scan2(
        const bf16* __restrict__ Qf, const bf16* __restrict__ L_in,
        const bf16* __restrict__ nUk_h, const bf16* __restrict__ nUk_l,
        const bf16* __restrict__ Kt_h, const bf16* __restrict__ Kt_l,
        const float* __restrict__ Uv_in, const float* __restrict__ gm,
        bf16* __restrict__ obf) {
    __shared__ bf16 ShT_h[64][72], ShT_l[64][72], Ut_h[64][72], Ut_l[64][72];
    const int tid = threadIdx.x, lane = tid & 63, w = tid >> 6;
    const int bh = blockIdx.x, b = bh >> 4, hh = bh & 15;
    const int col0 = hh * 64;
    for (int i = tid; i < 64 * 72; i += 256) {
        (&ShT_h[0][0])[i] = (bf16)0.f;
        (&ShT_l[0][0])[i] = (bf16)0.f;
    }
    __syncthreads();
    f32x4 Sacc[4];
#pragma unroll
    for (int vt = 0; vt < 4; ++vt) Sacc[vt] = (f32x4){0, 0, 0, 0};
    float gmv[4];
#pragma unroll
    for (int vt = 0; vt < 4; ++vt) gmv[vt] = gm[hh * 64 + vt * 16 + (lane & 15)];

    Frag fA, fB;
    auto offc = [&](int c) { return ((size_t)bh * 32 + c) * 4096; };
    load_frags(fA, nUk_h, nUk_l, Kt_h, Kt_l, L_in, Qf, Uv_in, offc(0), w, lane);
    for (int c = 0; c < 32; c += 2) {
        load_frags(fB, nUk_h, nUk_l, Kt_h, Kt_l, L_in, Qf, Uv_in, offc(c + 1), w, lane);
        compute_chunk(fA, Sacc, obf, gmv, b * TT + c * 64, col0, w, lane, ShT_h, ShT_l, Ut_h, Ut_l);
        if (c + 2 < 32)
            load_frags(fA, nUk_h, nUk_l, Kt_h, Kt_l, L_in, Qf, Uv_in, offc(c + 2), w, lane);
        compute_chunk(fB, Sacc, obf, gmv, b * TT + (c + 1) * 64, col0, w, lane, ShT_h, ShT_l, Ut_h, Ut_l);
    }
}

// ---------------- per-head RMSNorm * o_gamma, cast bf16 (row-major o, fallback path) ----------------
__global__ __launch_bounds__(256) void k_rms(const float* __restrict__ o, const float* __restrict__ gm,
                                             bf16* __restrict__ obf) {
    size_t row = (size_t)blockIdx.x * 4 + (threadIdx.x >> 6);
    int lane = threadIdx.x & 63;
    int h = (int)(row & 15);
    float x = o[row * 64 + lane];
    float ss = x * x;
#pragma unroll
    for (int m = 1; m < 64; m <<= 1) ss += __shfl_xor(ss, m);
    float y = x * rsqrtf(ss * (1.f / 64.f) + 1e-6f) * gm[h * 64 + lane];
    obf[row * 64 + lane] = (bf16)y;
}

// ---------------- residual + LayerNorm ----------------
__global__ __launch_bounds__(256) void k_ln(const float* __restrict__ yp, const float* __restrict__ x,
                                            const float* __restrict__ g, const float* __restrict__ bb,
                                            float* __restrict__ outp) {
    const int row = blockIdx.x;
    const int tid = threadIdx.x;
    __shared__ float red[8];
    const size_t base = (size_t)row * DD + tid * 4;
    float4 a  = *(const float4*)(yp + base);
    float4 b4 = *(const float4*)(x + base);
    float y0 = a.x + b4.x, y1 = a.y + b4.y, y2 = a.z + b4.z, y3 = a.w + b4.w;
    float s = (y0 + y1) + (y2 + y3);
#pragma unroll
    for (int m = 1; m < 64; m <<= 1) s += __shfl_xor(s, m);
    if ((tid & 63) == 0) red[tid >> 6] = s;
    __syncthreads();
    float mu = (red[0] + red[1] + red[2] + red[3]) * (1.f / (float)DD);
    float d0 = y0 - mu, d1 = y1 - mu, d2 = y2 - mu, d3 = y3 - mu;
    float sq = (d0 * d0 + d1 * d1) + (d2 * d2 + d3 * d3);
#pragma unroll
    for (int m = 1; m < 64; m <<= 1) sq += __shfl_xor(sq, m);
    if ((tid & 63) == 0) red[4 + (tid >> 6)] = sq;
    __syncthreads();
    float var = (red[4] + red[5] + red[6] + red[7]) * (1.f / (float)DD);
    float inv = rsqrtf(var + 1e-5f);
    const int c = tid * 4;
    float4 gg = *(const float4*)(g + c);
    float4 bv = *(const float4*)(bb + c);
    float4 r;
    r.x = d0 * inv * gg.x + bv.x;
    r.y = d1 * inv * gg.y + bv.y;
    r.z = d2 * inv * gg.z + bv.z;
    r.w = d3 * inv * gg.w + bv.w;
    *(float4*)(outp + base) = r;
}

// ---------------- launcher ----------------
extern "C" void kernel_launch(void* const* d_in, const int* in_sizes, int n_in,
                              void* d_out, int out_size, void* d_ws, size_t ws_size,
                              hipStream_t stream) {
    (void)in_sizes; (void)n_in; (void)out_size;
    if (ws_size < ((size_t)81 << 20)) return;
    const bool fast = ws_size >= ((size_t)137 << 20);

    const float* x   = (const float*)d_in[0];
    const float* Wq  = (const float*)d_in[1];
    const float* Wk  = (const float*)d_in[2];
    const float* Wv  = (const float*)d_in[3];
    const float* Wb  = (const float*)d_in[4];
    const float* gma = (const float*)d_in[5];
    const float* Wo  = (const float*)d_in[6];
    const float* lng = (const float*)d_in[7];
    const float* lnb = (const float*)d_in[8];
    float* outp = (float*)d_out;

    char* ws = (char*)d_ws;
    bf16*  xb    = (bf16*)(ws);                         // 8 MiB
    bf16*  WqT   = (bf16*)(ws + ((size_t)8  << 20));    // 2 MiB each
    bf16*  WoT   = (bf16*)(ws + ((size_t)14 << 20));
    float* q     = (float*)(ws + ((size_t)16 << 20));
    float* k     = (float*)(ws + ((size_t)32 << 20));
    float* v     = (float*)(ws + ((size_t)48 << 20));
    float* beta  = (float*)(ws + ((size_t)64 << 20));
    bf16*  wf    = (bf16*)(ws + ((size_t)64 << 20) + (1 << 19));  // 32 KiB frag-ordered Wb
    float* o     = (float*)(ws + ((size_t)65 << 20));   // fallback-path o (16 MiB)
    bf16*  Qfrag = (bf16*)(ws + ((size_t)65 << 20));    // fast-path Q fragments (8 MiB, reuses o slot)
    bf16*  obf   = (bf16*)(ws);                         // reuse xb
    float* yproj = (float*)(ws + ((size_t)16 << 20));   // reuse q (dead after prep: Qfrag holds Q)
    // chunked-scan scratch (fast path)
    bf16*  Lbf   = (bf16*)(ws + ((size_t)81  << 20));   // 8 MiB
    bf16*  nUk_h = (bf16*)(ws + ((size_t)89  << 20));
    bf16*  nUk_l = (bf16*)(ws + ((size_t)97  << 20));
    bf16*  Kt_h  = (bf16*)(ws + ((size_t)105 << 20));
    bf16*  Kt_l  = (bf16*)(ws + ((size_t)113 << 20));
    float* Uv    = (float*)(ws + ((size_t)121 << 20));  // 16 MiB

    bf16* WkT = WqT + (size_t)DD * DD;
    bf16* WvT = WkT + (size_t)DD * DD;

    k_wbfrag<<<8, 256, 0, stream>>>(Wb, wf);
    k_cvt<<<2048, 256, 0, stream>>>(x, xb);
    k_transpose_cvt4<<<dim3(16, 16, 4), 256, 0, stream>>>(Wq, Wk, Wv, Wo, WqT, WkT, WvT, WoT);
    k_gemm_qkv<<<dim3(32, 8, 3), 256, 0, stream>>>(xb, WqT, q);
    k_beta2<<<256, 64, 0, stream>>>(xb, wf, beta);
    k_actnorm<<<32768, 256, 0, stream>>>(q);   // q,k contiguous: one launch covers both
    if (fast) {
        k_prep<<<dim3(32, 32), 256, 0, stream>>>(q, k, v, beta, Lbf, nUk_h, nUk_l, Kt_h, Kt_l, Uv, Qfrag);
        k_scan2<<<32, 256, 0, stream>>>(Qfrag, Lbf, nUk_h, nUk_l, Kt_h, Kt_l, Uv, gma, obf);
    } else {
        k_scan<<<32, 256, 0, stream>>>(q, k, v, beta, o);
        k_rms<<<16384, 256, 0, stream>>>(o, gma, obf);
    }
    k_gemm<<<dim3(32, 8), 256, 0, stream>>>(obf, WoT, yproj);
    k_ln<<<4096, 256, 0, stream>>>(yproj, x, lng, lnb, outp);
}